// Round 8
// baseline (931.952 us; speedup 1.0000x reference)
//
#include <hip/hip_runtime.h>
#include <hip/hip_fp16.h>
#include <math.h>

#define CCAP 32
#define OVF_CAP 8192
#define BCAP 2560
#define BSHIFT 8

__device__ __forceinline__ float wsum(float v){
  #pragma unroll
  for (int o=32;o;o>>=1) v += __shfl_xor(v,o);
  return v;
}

// escal[l] = W_edge_row . (lin_edge_l @ att_e_l); escal[3+l] = b_edge . (...)
__global__ void k_edge_scalars(const float* __restrict__ lin_edge, // [3,64,64]
                               const float* __restrict__ att_e,   // [3,64]
                               const float* __restrict__ Wrow,    // [64]
                               const float* __restrict__ bemb,    // [64]
                               float* __restrict__ escal){
  int l = threadIdx.x >> 6, j = threadIdx.x & 63;
  float v = 0.f;
  for (int k=0;k<64;++k) v = fmaf(lin_edge[l*4096 + j*64 + k], att_e[l*64+k], v);
  float sv = wsum(Wrow[j]*v);
  float ov = wsum(bemb[j]*v);
  if (j==0){ escal[l]=sv; escal[3+l]=ov; }
}

// Weff[12][64] = W_cell @ lin0 ; beff[64] = b_cell @ lin0
__global__ void k_prepA(const float* __restrict__ W_cell, const float* __restrict__ b_cell,
                        const float* __restrict__ lin0, float* __restrict__ weff){
  int t = threadIdx.x;
  for (int o=t; o<832; o+=256){
    float acc = 0.f;
    if (o < 768){
      int r = o >> 6, c2 = o & 63;
      for (int c=0;c<64;++c) acc = fmaf(W_cell[r*64+c], lin0[c*64+c2], acc);
    } else {
      int c2 = o - 768;
      for (int c=0;c<64;++c) acc = fmaf(b_cell[c], lin0[c*64+c2], acc);
    }
    weff[o] = acc;
  }
}

// wv8[r] = W_well_r . (wc_lin @ att_d); wprep[8] = b_well . (wc_lin @ att_d)
__global__ void k_prepB(const float* __restrict__ W_well, const float* __restrict__ b_well,
                        const float* __restrict__ wc_lin, const float* __restrict__ att_d,
                        float* __restrict__ wprep){
  __shared__ float tmp[64];
  int t = threadIdx.x;
  if (t < 64){
    float a = 0.f;
    for (int c=0;c<64;++c) a = fmaf(wc_lin[t*64+c], att_d[c], a);
    tmp[t] = a;
  }
  __syncthreads();
  if (t < 9){
    float a = 0.f;
    if (t < 8){ for (int k=0;k<64;++k) a = fmaf(W_well[t*64+k], tmp[k], a); }
    else      { for (int k=0;k<64;++k) a = fmaf(b_well[k],     tmp[k], a); }
    wprep[t] = a;
  }
}

// ad_w[w] = well_x[w] . wv8 + woff
__global__ void k_well_ad2(const float* __restrict__ well_x, const float* __restrict__ wprep,
                           float* __restrict__ ad_w, int n){
  int w = blockIdx.x*blockDim.x + threadIdx.x;
  if (w >= n) return;
  float a = wprep[8];
  #pragma unroll
  for (int r=0;r<8;++r) a = fmaf(well_x[w*8+r], wprep[r], a);
  ad_w[w] = a;
}

// pass 1: append edges to coarse bins (atomic hands out consecutive slots ->
// concurrent writes to a bin coalesce). Fallback: direct scatter if bin full.
__global__ void k_bin(const int* __restrict__ src, const int* __restrict__ dst,
                      const float* __restrict__ attr, int* __restrict__ binc,
                      int4* __restrict__ bins, int* __restrict__ deg,
                      int2* __restrict__ slot, int4* __restrict__ ovf,
                      int* __restrict__ n_ovf, int e){
  int stride = gridDim.x*blockDim.x;
  for (int i = blockIdx.x*blockDim.x + threadIdx.x; i < e; i += stride){
    int d = dst[i];
    int b = d >> BSHIFT;
    int x = atomicAdd(&binc[b], 1);
    if (x < BCAP){
      bins[(size_t)b*BCAP + x] = make_int4(d, src[i], __float_as_int(attr[i]), 0);
    } else {
      // rare: bin overflow -> direct global scatter (claims deg slot before pass 2)
      int off = atomicAdd(&deg[d], 1);
      if (off < CCAP){
        slot[(d<<5) + off] = make_int2(src[i], __float_as_int(attr[i]));
      } else {
        int y = atomicAdd(n_ovf, 1);
        if (y < OVF_CAP) ovf[y] = make_int4(d, src[i], __float_as_int(attr[i]), 0);
      }
    }
  }
}

// pass 2: one workgroup per bin; scatter into final buckets within a 64KB
// L2-resident window (256 nodes x 32 slots x 8B).
__global__ void k_scatter(const int* __restrict__ binc, const int4* __restrict__ bins,
                          int* __restrict__ deg, int2* __restrict__ slot,
                          int4* __restrict__ ovf, int* __restrict__ n_ovf){
  int b = blockIdx.x;
  int cnt = binc[b]; if (cnt > BCAP) cnt = BCAP;
  const int4* mybin = bins + (size_t)b*BCAP;
  for (int j = threadIdx.x; j < cnt; j += blockDim.x){
    int4 e = mybin[j];
    int off = atomicAdd(&deg[e.x], 1);
    if (off < CCAP){
      slot[(e.x<<5) + off] = make_int2(e.y, e.z);
    } else {
      int y = atomicAdd(n_ovf, 1);
      if (y < OVF_CAP) ovf[y] = make_int4(e.x, e.y, e.z, 0);
    }
  }
}

// wells: count (record offset), scan, fill — tiny (65k edges / 512 wells)
__global__ void k_count_w(const int* __restrict__ dst, int* __restrict__ deg,
                          int* __restrict__ off, int e){
  int i = blockIdx.x*blockDim.x + threadIdx.x;
  if (i<e) off[i] = atomicAdd(&deg[dst[i]], 1);
}

__global__ void k_scan_single(const int* __restrict__ deg, int* __restrict__ rowptr, int n){
  __shared__ int sm[1024];
  int t = threadIdx.x;
  sm[t] = (t<n) ? deg[t] : 0; __syncthreads();
  for (int o=1;o<blockDim.x;o<<=1){
    int v = (t>=o)?sm[t-o]:0; __syncthreads();
    sm[t]+=v; __syncthreads();
  }
  if (t<n) rowptr[t+1]=sm[t];
  if (t==0) rowptr[0]=0;
}

__global__ void k_fill_w(const int* __restrict__ src, const int* __restrict__ dst,
                         const int* __restrict__ rowptr, const int* __restrict__ off,
                         int* __restrict__ slot, int e){
  int i = blockIdx.x*blockDim.x + threadIdx.x;
  if (i>=e) return;
  int d = dst[i];
  slot[rowptr[d] + off[i]] = src[i];
}

// hs[n,64](fp16) = h[n,64] @ W[64,64]; as_[i]=hs[i].att_s; ad_[i]=hs[i].att_d (f32)
__global__ __launch_bounds__(256) void k_gemm64(
    const float* __restrict__ h, const float* __restrict__ W,
    const float* __restrict__ att_s, const float* __restrict__ att_d,
    __half* __restrict__ hs, float* __restrict__ as_, float* __restrict__ ad_, int n){
  __shared__ float Ws[64*64];
  __shared__ float hT[64][68];
  int t = threadIdx.x;
  int n0 = blockIdx.x * 64;
  #pragma unroll
  for (int i=t;i<4096;i+=256) Ws[i] = W[i];
  for (int i=t;i<1024;i+=256){
    int node = i >> 4, k4 = (i & 15) << 2;
    int gn = n0 + node;
    float4 v = (gn < n) ? *(const float4*)&h[(size_t)gn*64 + k4] : make_float4(0,0,0,0);
    hT[k4+0][node]=v.x; hT[k4+1][node]=v.y; hT[k4+2][node]=v.z; hT[k4+3][node]=v.w;
  }
  __syncthreads();
  int tx = t & 15, ty = t >> 4;
  int f4 = tx*4;
  float acc[4][4] = {};
  for (int k=0;k<64;++k){
    float4 wv = *(const float4*)&Ws[k*64 + f4];
    float4 hv = *(const float4*)&hT[k][ty*4];
    float hvv[4] = {hv.x,hv.y,hv.z,hv.w};
    float wvv[4] = {wv.x,wv.y,wv.z,wv.w};
    #pragma unroll
    for (int i=0;i<4;++i)
      #pragma unroll
      for (int j=0;j<4;++j)
        acc[i][j] = fmaf(hvv[i], wvv[j], acc[i][j]);
  }
  float4 s4 = *(const float4*)&att_s[f4];
  float4 d4 = *(const float4*)&att_d[f4];
  #pragma unroll
  for (int i=0;i<4;++i){
    int gn = n0 + ty*4 + i;
    if (gn < n){
      union { __half2 h2; unsigned u; } lo, hi;
      lo.h2 = __floats2half2_rn(acc[i][0], acc[i][1]);
      hi.h2 = __floats2half2_rn(acc[i][2], acc[i][3]);
      *(int2*)&hs[(size_t)gn*64 + f4] = make_int2((int)lo.u, (int)hi.u);
      float sv = acc[i][0]*s4.x + acc[i][1]*s4.y + acc[i][2]*s4.z + acc[i][3]*s4.w;
      float dv = acc[i][0]*d4.x + acc[i][1]*d4.y + acc[i][2]*d4.z + acc[i][3]*d4.w;
      #pragma unroll
      for (int o=8;o;o>>=1){ sv += __shfl_xor(sv,o); dv += __shfl_xor(dv,o); }
      if (tx==0){ as_[gn]=sv; ad_[gn]=dv; }
    }
  }
}

// layer-0 fused: hs = x[n,12] @ Weff[12,64] + beff; epilogue as k_gemm64
__global__ __launch_bounds__(256) void k_gemm_l0(
    const float* __restrict__ x, const float* __restrict__ weff, // [832]: 12x64 + 64
    const float* __restrict__ att_s, const float* __restrict__ att_d,
    __half* __restrict__ hs, float* __restrict__ as_, float* __restrict__ ad_, int n){
  __shared__ float Ws[12*64];
  __shared__ float xT[12][68];
  int t = threadIdx.x;
  int n0 = blockIdx.x * 64;
  for (int i=t;i<768;i+=256){
    Ws[i] = weff[i];
    int node = i / 12, r = i - node*12;
    int gn = n0 + node;
    xT[r][node] = (gn < n) ? x[(size_t)gn*12 + r] : 0.f;
  }
  __syncthreads();
  int tx = t & 15, ty = t >> 4;
  int f4 = tx*4;
  float4 be = *(const float4*)&weff[768 + f4];
  float acc[4][4];
  #pragma unroll
  for (int i=0;i<4;++i){ acc[i][0]=be.x; acc[i][1]=be.y; acc[i][2]=be.z; acc[i][3]=be.w; }
  #pragma unroll
  for (int k=0;k<12;++k){
    float4 wv = *(const float4*)&Ws[k*64 + f4];
    float hvv[4];
    #pragma unroll
    for (int i=0;i<4;++i) hvv[i] = xT[k][ty*4+i];
    float wvv[4] = {wv.x,wv.y,wv.z,wv.w};
    #pragma unroll
    for (int i=0;i<4;++i)
      #pragma unroll
      for (int j=0;j<4;++j)
        acc[i][j] = fmaf(hvv[i], wvv[j], acc[i][j]);
  }
  float4 s4 = *(const float4*)&att_s[f4];
  float4 d4 = *(const float4*)&att_d[f4];
  #pragma unroll
  for (int i=0;i<4;++i){
    int gn = n0 + ty*4 + i;
    if (gn < n){
      union { __half2 h2; unsigned u; } lo, hi;
      lo.h2 = __floats2half2_rn(acc[i][0], acc[i][1]);
      hi.h2 = __floats2half2_rn(acc[i][2], acc[i][3]);
      *(int2*)&hs[(size_t)gn*64 + f4] = make_int2((int)lo.u, (int)hi.u);
      float sv = acc[i][0]*s4.x + acc[i][1]*s4.y + acc[i][2]*s4.z + acc[i][3]*s4.w;
      float dv = acc[i][0]*d4.x + acc[i][1]*d4.y + acc[i][2]*d4.z + acc[i][3]*d4.w;
      #pragma unroll
      for (int o=8;o;o>>=1){ sv += __shfl_xor(sv,o); dv += __shfl_xor(dv,o); }
      if (tx==0){ as_[gn]=sv; ad_[gn]=dv; }
    }
  }
}

// cell aggregation over fixed-stride buckets (CAP=32) + rare overflow list.
// 16-lane group per dst node; lane g holds features [4g,4g+4).
template<bool RELU>
__global__ __launch_bounds__(256) void k_gat_agg3(
    const int* __restrict__ deg, const int2* __restrict__ slot,
    const int4* __restrict__ ovf, const int* __restrict__ n_ovf_p,
    const float* __restrict__ as_, const float* __restrict__ ad_,
    const __half* __restrict__ hs, const float* __restrict__ bias,
    const float* __restrict__ escal, int l,
    float* __restrict__ out, int n){
  int t = threadIdx.x;
  int g = t & 15;
  int node = blockIdx.x*16 + (t >> 4);
  if (node >= n) return;
  int degn = deg[node];
  float4 b4 = *(const float4*)&bias[g*4];
  if (degn == 0){
    float4 r = b4;
    if (RELU){ r.x=fmaxf(r.x,0.f); r.y=fmaxf(r.y,0.f); r.z=fmaxf(r.z,0.f); r.w=fmaxf(r.w,0.f); }
    *(float4*)&out[(size_t)node*64 + g*4] = r;
    return;
  }
  float se = escal[l], oe = escal[3+l];
  float adn = ad_[node];
  int cin = min(degn, CCAP);
  int sb = node << 5;
  float areg[2]; int sreg[2];
  float m = -1e30f;
  #pragma unroll
  for (int it=0; it<2; ++it){
    int k = it*16 + g;
    areg[it] = -1e30f; sreg[it] = 0;
    if (k < cin){
      int2 sv = slot[sb + k];
      float a = as_[sv.x] + adn;
      a = fmaf(__int_as_float(sv.y), se, a) + oe;
      a = (a >= 0.f) ? a : 0.2f*a;
      areg[it] = a; sreg[it] = sv.x;
      m = fmaxf(m, a);
    }
  }
  int no = 0;
  if (degn > CCAP) no = min(*n_ovf_p, OVF_CAP);
  for (int j=0;j<no;++j){
    int4 e = ovf[j];
    if (e.x == node){
      float a = as_[e.y] + adn;
      a = fmaf(__int_as_float(e.z), se, a) + oe;
      a = (a >= 0.f) ? a : 0.2f*a;
      m = fmaxf(m, a);
    }
  }
  #pragma unroll
  for (int o=8;o;o>>=1) m = fmaxf(m, __shfl_xor(m, o, 16));

  float sum = 0.f;
  float4 acc = make_float4(0.f,0.f,0.f,0.f);
  #pragma unroll
  for (int it=0; it<2; ++it){
    int base = it*16;
    if (base < cin){
      float p = (base + g < cin) ? __expf(areg[it] - m) : 0.f;
      sum += p;
      int cnt = min(16, cin - base);
      for (int j=0;j<cnt;++j){
        float pj = __shfl(p, j, 16);
        int   sj = __shfl(sreg[it], j, 16);
        int2 hb = *(const int2*)&hs[(size_t)sj*64 + g*4];
        union { unsigned u; __half2 h2; } a0, a1; a0.u = (unsigned)hb.x; a1.u = (unsigned)hb.y;
        float2 f0 = __half22float2(a0.h2);
        float2 f1 = __half22float2(a1.h2);
        acc.x = fmaf(f0.x, pj, acc.x);
        acc.y = fmaf(f0.y, pj, acc.y);
        acc.z = fmaf(f1.x, pj, acc.z);
        acc.w = fmaf(f1.y, pj, acc.w);
      }
    }
  }
  for (int j=0;j<no;++j){
    int4 e = ovf[j];
    if (e.x == node){
      float a = as_[e.y] + adn;
      a = fmaf(__int_as_float(e.z), se, a) + oe;
      a = (a >= 0.f) ? a : 0.2f*a;
      float p = __expf(a - m);
      if (g == 0) sum += p;
      int2 hb = *(const int2*)&hs[(size_t)e.y*64 + g*4];
      union { unsigned u; __half2 h2; } a0, a1; a0.u = (unsigned)hb.x; a1.u = (unsigned)hb.y;
      float2 f0 = __half22float2(a0.h2);
      float2 f1 = __half22float2(a1.h2);
      acc.x = fmaf(f0.x, p, acc.x);
      acc.y = fmaf(f0.y, p, acc.y);
      acc.z = fmaf(f1.x, p, acc.z);
      acc.w = fmaf(f1.y, p, acc.w);
    }
  }
  #pragma unroll
  for (int o=8;o;o>>=1) sum += __shfl_xor(sum, o, 16);
  float4 r;
  r.x = acc.x/sum + b4.x;
  r.y = acc.y/sum + b4.y;
  r.z = acc.z/sum + b4.z;
  r.w = acc.w/sum + b4.w;
  if (RELU){ r.x=fmaxf(r.x,0.f); r.y=fmaxf(r.y,0.f); r.z=fmaxf(r.z,0.f); r.w=fmaxf(r.w,0.f); }
  *(float4*)&out[(size_t)node*64 + g*4] = r;
}

// well aggregation (CSR rowptr, int slots, no attr, no relu)
template<int NA>
__global__ __launch_bounds__(256) void k_gat_aggw(
    const int* __restrict__ rowptr, const int* __restrict__ slot1,
    float* __restrict__ alpha_ws,
    const float* __restrict__ as_, const float* __restrict__ ad_,
    const __half* __restrict__ hs, const float* __restrict__ bias,
    float* __restrict__ out, int n){
  int t = threadIdx.x;
  int g = t & 15;
  int node = blockIdx.x*16 + (t >> 4);
  if (node >= n) return;
  int beg = rowptr[node], end = rowptr[node+1];
  float4 b4 = *(const float4*)&bias[g*4];
  if (end == beg){
    *(float4*)&out[(size_t)node*64 + g*4] = b4;
    return;
  }
  float adn = ad_[node];
  float areg[NA]; int sreg[NA];
  float m = -1e30f;
  #pragma unroll
  for (int it=0; it<NA; ++it){
    int k = beg + it*16 + g;
    areg[it] = -1e30f; sreg[it] = 0;
    if (k < end){
      int s = slot1[k];
      float a = as_[s] + adn;
      a = (a >= 0.f) ? a : 0.2f*a;
      areg[it] = a; sreg[it] = s;
      m = fmaxf(m, a);
    }
  }
  for (int k = beg + NA*16 + g; k < end; k += 16){
    int s = slot1[k];
    float a = as_[s] + adn;
    a = (a >= 0.f) ? a : 0.2f*a;
    alpha_ws[k] = a;
    m = fmaxf(m, a);
  }
  #pragma unroll
  for (int o=8;o;o>>=1) m = fmaxf(m, __shfl_xor(m, o, 16));

  float sum = 0.f;
  float4 acc = make_float4(0.f,0.f,0.f,0.f);
  #pragma unroll
  for (int it=0; it<NA; ++it){
    int base = beg + it*16;
    if (base < end){
      float p = (base + g < end) ? __expf(areg[it] - m) : 0.f;
      sum += p;
      int cnt = min(16, end - base);
      for (int j=0;j<cnt;++j){
        float pj = __shfl(p, j, 16);
        int   sj = __shfl(sreg[it], j, 16);
        int2 hb = *(const int2*)&hs[(size_t)sj*64 + g*4];
        union { unsigned u; __half2 h2; } a0, a1; a0.u = (unsigned)hb.x; a1.u = (unsigned)hb.y;
        float2 f0 = __half22float2(a0.h2);
        float2 f1 = __half22float2(a1.h2);
        acc.x = fmaf(f0.x, pj, acc.x);
        acc.y = fmaf(f0.y, pj, acc.y);
        acc.z = fmaf(f1.x, pj, acc.z);
        acc.w = fmaf(f1.y, pj, acc.w);
      }
    }
  }
  for (int base = beg + NA*16; base < end; base += 16){
    int k = base + g;
    float p = 0.f; int s = 0;
    if (k < end){ s = slot1[k]; p = __expf(alpha_ws[k] - m); }
    sum += p;
    int cnt = min(16, end - base);
    for (int j=0;j<cnt;++j){
      float pj = __shfl(p, j, 16);
      int   sj = __shfl(s, j, 16);
      int2 hb = *(const int2*)&hs[(size_t)sj*64 + g*4];
      union { unsigned u; __half2 h2; } a0, a1; a0.u = (unsigned)hb.x; a1.u = (unsigned)hb.y;
      float2 f0 = __half22float2(a0.h2);
      float2 f1 = __half22float2(a1.h2);
      acc.x = fmaf(f0.x, pj, acc.x);
      acc.y = fmaf(f0.y, pj, acc.y);
      acc.z = fmaf(f1.x, pj, acc.z);
      acc.w = fmaf(f1.y, pj, acc.w);
    }
  }
  #pragma unroll
  for (int o=8;o;o>>=1) sum += __shfl_xor(sum, o, 16);
  float4 r;
  r.x = acc.x/sum + b4.x;
  r.y = acc.y/sum + b4.y;
  r.z = acc.z/sum + b4.z;
  r.w = acc.w/sum + b4.w;
  *(float4*)&out[(size_t)node*64 + g*4] = r;
}

__global__ __launch_bounds__(128) void k_mlp(const float* __restrict__ h_well,
    const float* __restrict__ W1, const float* __restrict__ b1,
    const float* __restrict__ W2, const float* __restrict__ b2,
    float* __restrict__ out, int n){
  __shared__ float hr[64]; __shared__ float h1[64];
  int w = blockIdx.x, t = threadIdx.x;
  if (t<64) hr[t] = h_well[w*64+t];
  __syncthreads();
  if (t<64){
    float a = b1[t];
    for (int k=0;k<64;++k) a = fmaf(hr[k], W1[k*64+t], a);
    h1[t] = fmaxf(a, 0.f);
  }
  __syncthreads();
  if (t<75){
    float a = b2[t];
    for (int k=0;k<64;++k) a = fmaf(h1[k], W2[k*75+t], a);
    out[w*75+t] = a;
  }
}

extern "C" void kernel_launch(void* const* d_in, const int* in_sizes, int n_in,
                              void* d_out, int out_size, void* d_ws, size_t ws_size,
                              hipStream_t stream){
  const float* cell_x = (const float*)d_in[0];
  const float* well_x = (const float*)d_in[1];
  const float* eattr  = (const float*)d_in[2];
  const int*   cc_idx = (const int*)d_in[3];
  const int*   cw_idx = (const int*)d_in[4];
  const float* W_cell = (const float*)d_in[5];
  const float* b_cell = (const float*)d_in[6];
  const float* W_well = (const float*)d_in[7];
  const float* b_well = (const float*)d_in[8];
  const float* W_edge = (const float*)d_in[9];
  const float* b_edge = (const float*)d_in[10];
  const float* conv_lin = (const float*)d_in[11];
  const float* conv_lin_edge = (const float*)d_in[12];
  const float* att_src = (const float*)d_in[13];
  const float* att_dst = (const float*)d_in[14];
  const float* att_edge = (const float*)d_in[15];
  const float* conv_bias = (const float*)d_in[16];
  const float* wc_lin = (const float*)d_in[17];
  const float* wc_att_src = (const float*)d_in[18];
  const float* wc_att_dst = (const float*)d_in[19];
  const float* wc_bias = (const float*)d_in[20];
  const float* mlp_W1 = (const float*)d_in[21];
  const float* mlp_b1 = (const float*)d_in[22];
  const float* mlp_W2 = (const float*)d_in[23];
  const float* mlp_b2 = (const float*)d_in[24];

  int n_cell = in_sizes[0]/12;
  int n_well = in_sizes[1]/8;
  int e_cc = in_sizes[2];
  int e_cw = in_sizes[4]/2;

  const int* cc_src = cc_idx;
  const int* cc_dst = cc_idx + e_cc;
  const int* cw_src = cw_idx;
  const int* cw_dst = cw_idx + e_cw;

  int nbin = (n_cell + (1<<BSHIFT) - 1) >> BSHIFT;

  char* p = (char*)d_ws;
  auto alloc = [&](size_t bytes)->void*{
    void* r = (void*)p;
    p += (bytes + 255) & ~(size_t)255;
    return r;
  };
  float* h_cur = (float*)alloc((size_t)n_cell*64*4);
  __half* hs   = (__half*)alloc((size_t)n_cell*64*2);
  float* as_   = (float*)alloc((size_t)n_cell*4);
  float* ad_   = (float*)alloc((size_t)n_cell*4);
  int* deg     = (int*)alloc((size_t)n_cell*4);
  int2* slot2  = (int2*)alloc((size_t)n_cell*CCAP*8);
  int4* bins   = (int4*)alloc((size_t)nbin*BCAP*16);
  int* binc    = (int*)alloc((size_t)nbin*4);
  int4* ovf    = (int4*)alloc((size_t)OVF_CAP*16);
  int* n_ovf   = (int*)alloc(256);
  float* ad_w  = (float*)alloc((size_t)n_well*4);
  int* wdeg    = (int*)alloc((size_t)n_well*4);
  int* wrowptr = (int*)alloc((size_t)(n_well+1)*4);
  int* woff    = (int*)alloc((size_t)e_cw*4);
  int* wslot   = (int*)alloc((size_t)e_cw*4);
  float* walpha= (float*)alloc((size_t)e_cw*4);
  float* h_well= (float*)alloc((size_t)n_well*64*4);
  float* escal = (float*)alloc(64);
  float* weff  = (float*)alloc(832*4);
  float* wprep = (float*)alloc(16*4);

  hipMemsetAsync(deg, 0, (size_t)n_cell*4, stream);
  hipMemsetAsync(binc, 0, (size_t)nbin*4, stream);
  hipMemsetAsync(wdeg, 0, (size_t)n_well*4, stream);
  hipMemsetAsync(n_ovf, 0, 4, stream);

  // precomputed small tensors
  k_edge_scalars<<<1, 192, 0, stream>>>(conv_lin_edge, att_edge, W_edge, b_edge, escal);
  k_prepA<<<1, 256, 0, stream>>>(W_cell, b_cell, conv_lin, weff);
  k_prepB<<<1, 128, 0, stream>>>(W_well, b_well, wc_lin, wc_att_dst, wprep);

  // two-level graph build: bin append (coalesced) then L2-local scatter
  k_bin<<<2048, 256, 0, stream>>>(cc_src, cc_dst, eattr, binc, bins, deg, slot2, ovf, n_ovf, e_cc);
  k_scatter<<<nbin, 256, 0, stream>>>(binc, bins, deg, slot2, ovf, n_ovf);

  // wells: exact CSR (tiny)
  k_count_w<<<(e_cw+255)/256, 256, 0, stream>>>(cw_dst, wdeg, woff, e_cw);
  k_scan_single<<<1, 512, 0, stream>>>(wdeg, wrowptr, n_well);
  k_fill_w<<<(e_cw+255)/256, 256, 0, stream>>>(cw_src, cw_dst, wrowptr, woff, wslot, e_cw);

  // layer 0: fused embed+gemm reading cell_x directly
  k_gemm_l0<<<(n_cell+63)/64, 256, 0, stream>>>(cell_x, weff,
      att_src, att_dst, hs, as_, ad_, n_cell);
  k_gat_agg3<true><<<(n_cell+15)/16, 256, 0, stream>>>(deg, slot2, ovf, n_ovf,
      as_, ad_, hs, conv_bias, escal, 0, h_cur, n_cell);

  // layers 1,2
  for (int l=1;l<3;++l){
    k_gemm64<<<(n_cell+63)/64, 256, 0, stream>>>(h_cur, conv_lin + l*4096,
        att_src + l*64, att_dst + l*64, hs, as_, ad_, n_cell);
    k_gat_agg3<true><<<(n_cell+15)/16, 256, 0, stream>>>(deg, slot2, ovf, n_ovf,
        as_, ad_, hs, conv_bias + l*64, escal, l, h_cur, n_cell);
  }

  // well GAT
  k_gemm64<<<(n_cell+63)/64, 256, 0, stream>>>(h_cur, wc_lin, wc_att_src, wc_att_dst,
      hs, as_, ad_, n_cell);
  k_well_ad2<<<(n_well+255)/256, 256, 0, stream>>>(well_x, wprep, ad_w, n_well);
  k_gat_aggw<16><<<(n_well+15)/16, 256, 0, stream>>>(wrowptr, wslot,
      walpha, as_, ad_w, hs, wc_bias, h_well, n_well);

  // MLP head
  k_mlp<<<n_well, 128, 0, stream>>>(h_well, mlp_W1, mlp_b1, mlp_W2, mlp_b2, (float*)d_out, n_well);
}

// Round 9
// 598.733 us; speedup vs baseline: 1.5565x; 1.5565x over previous
//
#include <hip/hip_runtime.h>
#include <hip/hip_fp16.h>
#include <math.h>

#define CCAP 32
#define OVF_CAP 8192

__device__ __forceinline__ float wsum(float v){
  #pragma unroll
  for (int o=32;o;o>>=1) v += __shfl_xor(v,o);
  return v;
}

// escal[l] = W_edge_row . (lin_edge_l @ att_e_l); escal[3+l] = b_edge . (...)
__global__ void k_edge_scalars(const float* __restrict__ lin_edge, // [3,64,64]
                               const float* __restrict__ att_e,   // [3,64]
                               const float* __restrict__ Wrow,    // [64]
                               const float* __restrict__ bemb,    // [64]
                               float* __restrict__ escal){
  int l = threadIdx.x >> 6, j = threadIdx.x & 63;
  float v = 0.f;
  for (int k=0;k<64;++k) v = fmaf(lin_edge[l*4096 + j*64 + k], att_e[l*64+k], v);
  float sv = wsum(Wrow[j]*v);
  float ov = wsum(bemb[j]*v);
  if (j==0){ escal[l]=sv; escal[3+l]=ov; }
}

// Weff[12][64] = W_cell @ lin0 ; beff[64] = b_cell @ lin0
__global__ void k_prepA(const float* __restrict__ W_cell, const float* __restrict__ b_cell,
                        const float* __restrict__ lin0, float* __restrict__ weff){
  int t = threadIdx.x;
  for (int o=t; o<832; o+=256){
    float acc = 0.f;
    if (o < 768){
      int r = o >> 6, c2 = o & 63;
      for (int c=0;c<64;++c) acc = fmaf(W_cell[r*64+c], lin0[c*64+c2], acc);
    } else {
      int c2 = o - 768;
      for (int c=0;c<64;++c) acc = fmaf(b_cell[c], lin0[c*64+c2], acc);
    }
    weff[o] = acc;
  }
}

// wv8[r] = W_well_r . (wc_lin @ att_d); wprep[8] = b_well . (wc_lin @ att_d)
__global__ void k_prepB(const float* __restrict__ W_well, const float* __restrict__ b_well,
                        const float* __restrict__ wc_lin, const float* __restrict__ att_d,
                        float* __restrict__ wprep){
  __shared__ float tmp[64];
  int t = threadIdx.x;
  if (t < 64){
    float a = 0.f;
    for (int c=0;c<64;++c) a = fmaf(wc_lin[t*64+c], att_d[c], a);
    tmp[t] = a;
  }
  __syncthreads();
  if (t < 9){
    float a = 0.f;
    if (t < 8){ for (int k=0;k<64;++k) a = fmaf(W_well[t*64+k], tmp[k], a); }
    else      { for (int k=0;k<64;++k) a = fmaf(b_well[k],     tmp[k], a); }
    wprep[t] = a;
  }
}

// ad_w[w] = well_x[w] . wv8 + woff
__global__ void k_well_ad2(const float* __restrict__ well_x, const float* __restrict__ wprep,
                           float* __restrict__ ad_w, int n){
  int w = blockIdx.x*blockDim.x + threadIdx.x;
  if (w >= n) return;
  float a = wprep[8];
  #pragma unroll
  for (int r=0;r<8;++r) a = fmaf(well_x[w*8+r], wprep[r], a);
  ad_w[w] = a;
}

// single-pass cell bucket build: one atomic + one 8B scatter per edge
__global__ void k_build_cc(const int* __restrict__ src, const int* __restrict__ dst,
                           const float* __restrict__ attr, int* __restrict__ deg,
                           int2* __restrict__ slot, int4* __restrict__ ovf,
                           int* __restrict__ n_ovf, int e){
  int stride = gridDim.x*blockDim.x;
  for (int i = blockIdx.x*blockDim.x + threadIdx.x; i < e; i += stride){
    int d = dst[i];
    int off = atomicAdd(&deg[d], 1);
    if (off < CCAP){
      slot[(d<<5) + off] = make_int2(src[i], __float_as_int(attr[i]));
    } else {
      int x = atomicAdd(n_ovf, 1);
      if (x < OVF_CAP) ovf[x] = make_int4(d, src[i], __float_as_int(attr[i]), 0);
    }
  }
}

// wells: count (record offset), scan, fill — tiny (65k edges / 512 wells)
__global__ void k_count_w(const int* __restrict__ dst, int* __restrict__ deg,
                          int* __restrict__ off, int e){
  int i = blockIdx.x*blockDim.x + threadIdx.x;
  if (i<e) off[i] = atomicAdd(&deg[dst[i]], 1);
}

__global__ void k_scan_single(const int* __restrict__ deg, int* __restrict__ rowptr, int n){
  __shared__ int sm[1024];
  int t = threadIdx.x;
  sm[t] = (t<n) ? deg[t] : 0; __syncthreads();
  for (int o=1;o<blockDim.x;o<<=1){
    int v = (t>=o)?sm[t-o]:0; __syncthreads();
    sm[t]+=v; __syncthreads();
  }
  if (t<n) rowptr[t+1]=sm[t];
  if (t==0) rowptr[0]=0;
}

__global__ void k_fill_w(const int* __restrict__ src, const int* __restrict__ dst,
                         const int* __restrict__ rowptr, const int* __restrict__ off,
                         int* __restrict__ slot, int e){
  int i = blockIdx.x*blockDim.x + threadIdx.x;
  if (i>=e) return;
  int d = dst[i];
  slot[rowptr[d] + off[i]] = src[i];
}

// hs[n,64](fp16) = h[n,64] @ W[64,64]; as_[i]=hs[i].att_s; ad_[i]=hs[i].att_d (f32)
__global__ __launch_bounds__(256) void k_gemm64(
    const float* __restrict__ h, const float* __restrict__ W,
    const float* __restrict__ att_s, const float* __restrict__ att_d,
    __half* __restrict__ hs, float* __restrict__ as_, float* __restrict__ ad_, int n){
  __shared__ float Ws[64*64];
  __shared__ float hT[64][68];
  int t = threadIdx.x;
  int n0 = blockIdx.x * 64;
  #pragma unroll
  for (int i=t;i<4096;i+=256) Ws[i] = W[i];
  for (int i=t;i<1024;i+=256){
    int node = i >> 4, k4 = (i & 15) << 2;
    int gn = n0 + node;
    float4 v = (gn < n) ? *(const float4*)&h[(size_t)gn*64 + k4] : make_float4(0,0,0,0);
    hT[k4+0][node]=v.x; hT[k4+1][node]=v.y; hT[k4+2][node]=v.z; hT[k4+3][node]=v.w;
  }
  __syncthreads();
  int tx = t & 15, ty = t >> 4;
  int f4 = tx*4;
  float acc[4][4] = {};
  for (int k=0;k<64;++k){
    float4 wv = *(const float4*)&Ws[k*64 + f4];
    float4 hv = *(const float4*)&hT[k][ty*4];
    float hvv[4] = {hv.x,hv.y,hv.z,hv.w};
    float wvv[4] = {wv.x,wv.y,wv.z,wv.w};
    #pragma unroll
    for (int i=0;i<4;++i)
      #pragma unroll
      for (int j=0;j<4;++j)
        acc[i][j] = fmaf(hvv[i], wvv[j], acc[i][j]);
  }
  float4 s4 = *(const float4*)&att_s[f4];
  float4 d4 = *(const float4*)&att_d[f4];
  #pragma unroll
  for (int i=0;i<4;++i){
    int gn = n0 + ty*4 + i;
    if (gn < n){
      union { __half2 h2; unsigned u; } lo, hi;
      lo.h2 = __floats2half2_rn(acc[i][0], acc[i][1]);
      hi.h2 = __floats2half2_rn(acc[i][2], acc[i][3]);
      *(int2*)&hs[(size_t)gn*64 + f4] = make_int2((int)lo.u, (int)hi.u);
      float sv = acc[i][0]*s4.x + acc[i][1]*s4.y + acc[i][2]*s4.z + acc[i][3]*s4.w;
      float dv = acc[i][0]*d4.x + acc[i][1]*d4.y + acc[i][2]*d4.z + acc[i][3]*d4.w;
      #pragma unroll
      for (int o=8;o;o>>=1){ sv += __shfl_xor(sv,o); dv += __shfl_xor(dv,o); }
      if (tx==0){ as_[gn]=sv; ad_[gn]=dv; }
    }
  }
}

// layer-0 fused: hs = x[n,12] @ Weff[12,64] + beff; epilogue as k_gemm64
__global__ __launch_bounds__(256) void k_gemm_l0(
    const float* __restrict__ x, const float* __restrict__ weff, // [832]: 12x64 + 64
    const float* __restrict__ att_s, const float* __restrict__ att_d,
    __half* __restrict__ hs, float* __restrict__ as_, float* __restrict__ ad_, int n){
  __shared__ float Ws[12*64];
  __shared__ float xT[12][68];
  int t = threadIdx.x;
  int n0 = blockIdx.x * 64;
  for (int i=t;i<768;i+=256){
    Ws[i] = weff[i];
    int node = i / 12, r = i - node*12;
    int gn = n0 + node;
    xT[r][node] = (gn < n) ? x[(size_t)gn*12 + r] : 0.f;
  }
  __syncthreads();
  int tx = t & 15, ty = t >> 4;
  int f4 = tx*4;
  float4 be = *(const float4*)&weff[768 + f4];
  float acc[4][4];
  #pragma unroll
  for (int i=0;i<4;++i){ acc[i][0]=be.x; acc[i][1]=be.y; acc[i][2]=be.z; acc[i][3]=be.w; }
  #pragma unroll
  for (int k=0;k<12;++k){
    float4 wv = *(const float4*)&Ws[k*64 + f4];
    float hvv[4];
    #pragma unroll
    for (int i=0;i<4;++i) hvv[i] = xT[k][ty*4+i];
    float wvv[4] = {wv.x,wv.y,wv.z,wv.w};
    #pragma unroll
    for (int i=0;i<4;++i)
      #pragma unroll
      for (int j=0;j<4;++j)
        acc[i][j] = fmaf(hvv[i], wvv[j], acc[i][j]);
  }
  float4 s4 = *(const float4*)&att_s[f4];
  float4 d4 = *(const float4*)&att_d[f4];
  #pragma unroll
  for (int i=0;i<4;++i){
    int gn = n0 + ty*4 + i;
    if (gn < n){
      union { __half2 h2; unsigned u; } lo, hi;
      lo.h2 = __floats2half2_rn(acc[i][0], acc[i][1]);
      hi.h2 = __floats2half2_rn(acc[i][2], acc[i][3]);
      *(int2*)&hs[(size_t)gn*64 + f4] = make_int2((int)lo.u, (int)hi.u);
      float sv = acc[i][0]*s4.x + acc[i][1]*s4.y + acc[i][2]*s4.z + acc[i][3]*s4.w;
      float dv = acc[i][0]*d4.x + acc[i][1]*d4.y + acc[i][2]*d4.z + acc[i][3]*d4.w;
      #pragma unroll
      for (int o=8;o;o>>=1){ sv += __shfl_xor(sv,o); dv += __shfl_xor(dv,o); }
      if (tx==0){ as_[gn]=sv; ad_[gn]=dv; }
    }
  }
}

// cell aggregation over fixed-stride buckets (CAP=32) + rare overflow list.
// 16-lane group per dst node; lane g holds features [4g,4g+4).
// gather loop unrolled x4: 4 independent hs-row loads in flight per step.
template<bool RELU>
__global__ __launch_bounds__(256) void k_gat_agg3(
    const int* __restrict__ deg, const int2* __restrict__ slot,
    const int4* __restrict__ ovf, const int* __restrict__ n_ovf_p,
    const float* __restrict__ as_, const float* __restrict__ ad_,
    const __half* __restrict__ hs, const float* __restrict__ bias,
    const float* __restrict__ escal, int l,
    float* __restrict__ out, int n){
  int t = threadIdx.x;
  int g = t & 15;
  int node = blockIdx.x*16 + (t >> 4);
  if (node >= n) return;
  int degn = deg[node];
  float4 b4 = *(const float4*)&bias[g*4];
  if (degn == 0){
    float4 r = b4;
    if (RELU){ r.x=fmaxf(r.x,0.f); r.y=fmaxf(r.y,0.f); r.z=fmaxf(r.z,0.f); r.w=fmaxf(r.w,0.f); }
    *(float4*)&out[(size_t)node*64 + g*4] = r;
    return;
  }
  float se = escal[l], oe = escal[3+l];
  float adn = ad_[node];
  int cin = min(degn, CCAP);
  int sb = node << 5;
  float areg[2]; int sreg[2];
  float m = -1e30f;
  #pragma unroll
  for (int it=0; it<2; ++it){
    int k = it*16 + g;
    areg[it] = -1e30f; sreg[it] = 0;
    if (k < cin){
      int2 sv = slot[sb + k];
      float a = as_[sv.x] + adn;
      a = fmaf(__int_as_float(sv.y), se, a) + oe;
      a = (a >= 0.f) ? a : 0.2f*a;
      areg[it] = a; sreg[it] = sv.x;
      m = fmaxf(m, a);
    }
  }
  int no = 0;
  if (degn > CCAP) no = min(*n_ovf_p, OVF_CAP);
  for (int j=0;j<no;++j){
    int4 e = ovf[j];
    if (e.x == node){
      float a = as_[e.y] + adn;
      a = fmaf(__int_as_float(e.z), se, a) + oe;
      a = (a >= 0.f) ? a : 0.2f*a;
      m = fmaxf(m, a);
    }
  }
  #pragma unroll
  for (int o=8;o;o>>=1) m = fmaxf(m, __shfl_xor(m, o, 16));

  float sum = 0.f;
  float4 acc = make_float4(0.f,0.f,0.f,0.f);
  #pragma unroll
  for (int it=0; it<2; ++it){
    int base = it*16;
    if (base < cin){
      float p = (base + g < cin) ? __expf(areg[it] - m) : 0.f;
      sum += p;
      int cnt = min(16, cin - base);
      for (int j=0;j<cnt;j+=4){
        float pj[4]; int sj[4];
        int s0 = __shfl(sreg[it], j, 16);
        #pragma unroll
        for (int u=0;u<4;++u){
          int jj = j+u;
          bool act = (jj < cnt);
          pj[u] = act ? __shfl(p, jj, 16) : 0.f;
          int sv = __shfl(sreg[it], act ? jj : j, 16);
          sj[u] = act ? sv : s0;
        }
        int2 hb[4];
        #pragma unroll
        for (int u=0;u<4;++u) hb[u] = *(const int2*)&hs[(size_t)sj[u]*64 + g*4];
        #pragma unroll
        for (int u=0;u<4;++u){
          union { unsigned u32; __half2 h2; } a0, a1;
          a0.u32 = (unsigned)hb[u].x; a1.u32 = (unsigned)hb[u].y;
          float2 f0 = __half22float2(a0.h2);
          float2 f1 = __half22float2(a1.h2);
          acc.x = fmaf(f0.x, pj[u], acc.x);
          acc.y = fmaf(f0.y, pj[u], acc.y);
          acc.z = fmaf(f1.x, pj[u], acc.z);
          acc.w = fmaf(f1.y, pj[u], acc.w);
        }
      }
    }
  }
  for (int j=0;j<no;++j){
    int4 e = ovf[j];
    if (e.x == node){
      float a = as_[e.y] + adn;
      a = fmaf(__int_as_float(e.z), se, a) + oe;
      a = (a >= 0.f) ? a : 0.2f*a;
      float p = __expf(a - m);
      if (g == 0) sum += p;
      int2 hb = *(const int2*)&hs[(size_t)e.y*64 + g*4];
      union { unsigned u; __half2 h2; } a0, a1; a0.u = (unsigned)hb.x; a1.u = (unsigned)hb.y;
      float2 f0 = __half22float2(a0.h2);
      float2 f1 = __half22float2(a1.h2);
      acc.x = fmaf(f0.x, p, acc.x);
      acc.y = fmaf(f0.y, p, acc.y);
      acc.z = fmaf(f1.x, p, acc.z);
      acc.w = fmaf(f1.y, p, acc.w);
    }
  }
  #pragma unroll
  for (int o=8;o;o>>=1) sum += __shfl_xor(sum, o, 16);
  float4 r;
  r.x = acc.x/sum + b4.x;
  r.y = acc.y/sum + b4.y;
  r.z = acc.z/sum + b4.z;
  r.w = acc.w/sum + b4.w;
  if (RELU){ r.x=fmaxf(r.x,0.f); r.y=fmaxf(r.y,0.f); r.z=fmaxf(r.z,0.f); r.w=fmaxf(r.w,0.f); }
  *(float4*)&out[(size_t)node*64 + g*4] = r;
}

// well aggregation (CSR rowptr, int slots, no attr, no relu)
template<int NA>
__global__ __launch_bounds__(256) void k_gat_aggw(
    const int* __restrict__ rowptr, const int* __restrict__ slot1,
    float* __restrict__ alpha_ws,
    const float* __restrict__ as_, const float* __restrict__ ad_,
    const __half* __restrict__ hs, const float* __restrict__ bias,
    float* __restrict__ out, int n){
  int t = threadIdx.x;
  int g = t & 15;
  int node = blockIdx.x*16 + (t >> 4);
  if (node >= n) return;
  int beg = rowptr[node], end = rowptr[node+1];
  float4 b4 = *(const float4*)&bias[g*4];
  if (end == beg){
    *(float4*)&out[(size_t)node*64 + g*4] = b4;
    return;
  }
  float adn = ad_[node];
  float areg[NA]; int sreg[NA];
  float m = -1e30f;
  #pragma unroll
  for (int it=0; it<NA; ++it){
    int k = beg + it*16 + g;
    areg[it] = -1e30f; sreg[it] = 0;
    if (k < end){
      int s = slot1[k];
      float a = as_[s] + adn;
      a = (a >= 0.f) ? a : 0.2f*a;
      areg[it] = a; sreg[it] = s;
      m = fmaxf(m, a);
    }
  }
  for (int k = beg + NA*16 + g; k < end; k += 16){
    int s = slot1[k];
    float a = as_[s] + adn;
    a = (a >= 0.f) ? a : 0.2f*a;
    alpha_ws[k] = a;
    m = fmaxf(m, a);
  }
  #pragma unroll
  for (int o=8;o;o>>=1) m = fmaxf(m, __shfl_xor(m, o, 16));

  float sum = 0.f;
  float4 acc = make_float4(0.f,0.f,0.f,0.f);
  #pragma unroll
  for (int it=0; it<NA; ++it){
    int base = beg + it*16;
    if (base < end){
      float p = (base + g < end) ? __expf(areg[it] - m) : 0.f;
      sum += p;
      int cnt = min(16, end - base);
      for (int j=0;j<cnt;++j){
        float pj = __shfl(p, j, 16);
        int   sj = __shfl(sreg[it], j, 16);
        int2 hb = *(const int2*)&hs[(size_t)sj*64 + g*4];
        union { unsigned u; __half2 h2; } a0, a1; a0.u = (unsigned)hb.x; a1.u = (unsigned)hb.y;
        float2 f0 = __half22float2(a0.h2);
        float2 f1 = __half22float2(a1.h2);
        acc.x = fmaf(f0.x, pj, acc.x);
        acc.y = fmaf(f0.y, pj, acc.y);
        acc.z = fmaf(f1.x, pj, acc.z);
        acc.w = fmaf(f1.y, pj, acc.w);
      }
    }
  }
  for (int base = beg + NA*16; base < end; base += 16){
    int k = base + g;
    float p = 0.f; int s = 0;
    if (k < end){ s = slot1[k]; p = __expf(alpha_ws[k] - m); }
    sum += p;
    int cnt = min(16, end - base);
    for (int j=0;j<cnt;++j){
      float pj = __shfl(p, j, 16);
      int   sj = __shfl(s, j, 16);
      int2 hb = *(const int2*)&hs[(size_t)sj*64 + g*4];
      union { unsigned u; __half2 h2; } a0, a1; a0.u = (unsigned)hb.x; a1.u = (unsigned)hb.y;
      float2 f0 = __half22float2(a0.h2);
      float2 f1 = __half22float2(a1.h2);
      acc.x = fmaf(f0.x, pj, acc.x);
      acc.y = fmaf(f0.y, pj, acc.y);
      acc.z = fmaf(f1.x, pj, acc.z);
      acc.w = fmaf(f1.y, pj, acc.w);
    }
  }
  #pragma unroll
  for (int o=8;o;o>>=1) sum += __shfl_xor(sum, o, 16);
  float4 r;
  r.x = acc.x/sum + b4.x;
  r.y = acc.y/sum + b4.y;
  r.z = acc.z/sum + b4.z;
  r.w = acc.w/sum + b4.w;
  *(float4*)&out[(size_t)node*64 + g*4] = r;
}

__global__ __launch_bounds__(128) void k_mlp(const float* __restrict__ h_well,
    const float* __restrict__ W1, const float* __restrict__ b1,
    const float* __restrict__ W2, const float* __restrict__ b2,
    float* __restrict__ out, int n){
  __shared__ float hr[64]; __shared__ float h1[64];
  int w = blockIdx.x, t = threadIdx.x;
  if (t<64) hr[t] = h_well[w*64+t];
  __syncthreads();
  if (t<64){
    float a = b1[t];
    for (int k=0;k<64;++k) a = fmaf(hr[k], W1[k*64+t], a);
    h1[t] = fmaxf(a, 0.f);
  }
  __syncthreads();
  if (t<75){
    float a = b2[t];
    for (int k=0;k<64;++k) a = fmaf(h1[k], W2[k*75+t], a);
    out[w*75+t] = a;
  }
}

extern "C" void kernel_launch(void* const* d_in, const int* in_sizes, int n_in,
                              void* d_out, int out_size, void* d_ws, size_t ws_size,
                              hipStream_t stream){
  const float* cell_x = (const float*)d_in[0];
  const float* well_x = (const float*)d_in[1];
  const float* eattr  = (const float*)d_in[2];
  const int*   cc_idx = (const int*)d_in[3];
  const int*   cw_idx = (const int*)d_in[4];
  const float* W_cell = (const float*)d_in[5];
  const float* b_cell = (const float*)d_in[6];
  const float* W_well = (const float*)d_in[7];
  const float* b_well = (const float*)d_in[8];
  const float* W_edge = (const float*)d_in[9];
  const float* b_edge = (const float*)d_in[10];
  const float* conv_lin = (const float*)d_in[11];
  const float* conv_lin_edge = (const float*)d_in[12];
  const float* att_src = (const float*)d_in[13];
  const float* att_dst = (const float*)d_in[14];
  const float* att_edge = (const float*)d_in[15];
  const float* conv_bias = (const float*)d_in[16];
  const float* wc_lin = (const float*)d_in[17];
  const float* wc_att_src = (const float*)d_in[18];
  const float* wc_att_dst = (const float*)d_in[19];
  const float* wc_bias = (const float*)d_in[20];
  const float* mlp_W1 = (const float*)d_in[21];
  const float* mlp_b1 = (const float*)d_in[22];
  const float* mlp_W2 = (const float*)d_in[23];
  const float* mlp_b2 = (const float*)d_in[24];

  int n_cell = in_sizes[0]/12;
  int n_well = in_sizes[1]/8;
  int e_cc = in_sizes[2];
  int e_cw = in_sizes[4]/2;

  const int* cc_src = cc_idx;
  const int* cc_dst = cc_idx + e_cc;
  const int* cw_src = cw_idx;
  const int* cw_dst = cw_idx + e_cw;

  char* p = (char*)d_ws;
  auto alloc = [&](size_t bytes)->void*{
    void* r = (void*)p;
    p += (bytes + 255) & ~(size_t)255;
    return r;
  };
  float* h_cur = (float*)alloc((size_t)n_cell*64*4);
  __half* hs   = (__half*)alloc((size_t)n_cell*64*2);
  float* as_   = (float*)alloc((size_t)n_cell*4);
  float* ad_   = (float*)alloc((size_t)n_cell*4);
  int* deg     = (int*)alloc((size_t)n_cell*4);
  int2* slot2  = (int2*)alloc((size_t)n_cell*CCAP*8);
  int4* ovf    = (int4*)alloc((size_t)OVF_CAP*16);
  int* n_ovf   = (int*)alloc(256);
  float* ad_w  = (float*)alloc((size_t)n_well*4);
  int* wdeg    = (int*)alloc((size_t)n_well*4);
  int* wrowptr = (int*)alloc((size_t)(n_well+1)*4);
  int* woff    = (int*)alloc((size_t)e_cw*4);
  int* wslot   = (int*)alloc((size_t)e_cw*4);
  float* walpha= (float*)alloc((size_t)e_cw*4);
  float* h_well= (float*)alloc((size_t)n_well*64*4);
  float* escal = (float*)alloc(64);
  float* weff  = (float*)alloc(832*4);
  float* wprep = (float*)alloc(16*4);

  hipMemsetAsync(deg, 0, (size_t)n_cell*4, stream);
  hipMemsetAsync(wdeg, 0, (size_t)n_well*4, stream);
  hipMemsetAsync(n_ovf, 0, 4, stream);

  // precomputed small tensors
  k_edge_scalars<<<1, 192, 0, stream>>>(conv_lin_edge, att_edge, W_edge, b_edge, escal);
  k_prepA<<<1, 256, 0, stream>>>(W_cell, b_cell, conv_lin, weff);
  k_prepB<<<1, 128, 0, stream>>>(W_well, b_well, wc_lin, wc_att_dst, wprep);

  // single-pass cell bucket build
  int gB = (e_cc + 255)/256; if (gB > 2048) gB = 2048;
  k_build_cc<<<gB, 256, 0, stream>>>(cc_src, cc_dst, eattr, deg, slot2, ovf, n_ovf, e_cc);

  // wells: exact CSR (tiny)
  k_count_w<<<(e_cw+255)/256, 256, 0, stream>>>(cw_dst, wdeg, woff, e_cw);
  k_scan_single<<<1, 512, 0, stream>>>(wdeg, wrowptr, n_well);
  k_fill_w<<<(e_cw+255)/256, 256, 0, stream>>>(cw_src, cw_dst, wrowptr, woff, wslot, e_cw);

  // layer 0: fused embed+gemm reading cell_x directly
  k_gemm_l0<<<(n_cell+63)/64, 256, 0, stream>>>(cell_x, weff,
      att_src, att_dst, hs, as_, ad_, n_cell);
  k_gat_agg3<true><<<(n_cell+15)/16, 256, 0, stream>>>(deg, slot2, ovf, n_ovf,
      as_, ad_, hs, conv_bias, escal, 0, h_cur, n_cell);

  // layers 1,2
  for (int l=1;l<3;++l){
    k_gemm64<<<(n_cell+63)/64, 256, 0, stream>>>(h_cur, conv_lin + l*4096,
        att_src + l*64, att_dst + l*64, hs, as_, ad_, n_cell);
    k_gat_agg3<true><<<(n_cell+15)/16, 256, 0, stream>>>(deg, slot2, ovf, n_ovf,
        as_, ad_, hs, conv_bias + l*64, escal, l, h_cur, n_cell);
  }

  // well GAT
  k_gemm64<<<(n_cell+63)/64, 256, 0, stream>>>(h_cur, wc_lin, wc_att_src, wc_att_dst,
      hs, as_, ad_, n_cell);
  k_well_ad2<<<(n_well+255)/256, 256, 0, stream>>>(well_x, wprep, ad_w, n_well);
  k_gat_aggw<16><<<(n_well+15)/16, 256, 0, stream>>>(wrowptr, wslot,
      walpha, as_, ad_w, hs, wc_bias, h_well, n_well);

  // MLP head
  k_mlp<<<n_well, 128, 0, stream>>>(h_well, mlp_W1, mlp_b1, mlp_W2, mlp_b2, (float*)d_out, n_well);
}

// Round 10
// 534.123 us; speedup vs baseline: 1.7448x; 1.1210x over previous
//
#include <hip/hip_runtime.h>
#include <hip/hip_fp16.h>
#include <math.h>

#define CCAP 32
#define OVF_CAP 8192

typedef __attribute__((ext_vector_type(8))) _Float16 f16x8;
typedef __attribute__((ext_vector_type(4))) float f32x4;

__device__ __forceinline__ float wsum(float v){
  #pragma unroll
  for (int o=32;o;o>>=1) v += __shfl_xor(v,o);
  return v;
}

// escal[l] = W_edge_row . (lin_edge_l @ att_e_l); escal[3+l] = b_edge . (...)
__global__ void k_edge_scalars(const float* __restrict__ lin_edge,
                               const float* __restrict__ att_e,
                               const float* __restrict__ Wrow,
                               const float* __restrict__ bemb,
                               float* __restrict__ escal){
  int l = threadIdx.x >> 6, j = threadIdx.x & 63;
  float v = 0.f;
  for (int k=0;k<64;++k) v = fmaf(lin_edge[l*4096 + j*64 + k], att_e[l*64+k], v);
  float sv = wsum(Wrow[j]*v);
  float ov = wsum(bemb[j]*v);
  if (j==0){ escal[l]=sv; escal[3+l]=ov; }
}

// Weff[12][64] = W_cell @ lin0 ; beff[64] = b_cell @ lin0
__global__ void k_prepA(const float* __restrict__ W_cell, const float* __restrict__ b_cell,
                        const float* __restrict__ lin0, float* __restrict__ weff){
  int t = threadIdx.x;
  for (int o=t; o<832; o+=256){
    float acc = 0.f;
    if (o < 768){
      int r = o >> 6, c2 = o & 63;
      for (int c=0;c<64;++c) acc = fmaf(W_cell[r*64+c], lin0[c*64+c2], acc);
    } else {
      int c2 = o - 768;
      for (int c=0;c<64;++c) acc = fmaf(b_cell[c], lin0[c*64+c2], acc);
    }
    weff[o] = acc;
  }
}

// wv8[r] = W_well_r . (wc_lin @ att_d); wprep[8] = b_well . (wc_lin @ att_d)
__global__ void k_prepB(const float* __restrict__ W_well, const float* __restrict__ b_well,
                        const float* __restrict__ wc_lin, const float* __restrict__ att_d,
                        float* __restrict__ wprep){
  __shared__ float tmp[64];
  int t = threadIdx.x;
  if (t < 64){
    float a = 0.f;
    for (int c=0;c<64;++c) a = fmaf(wc_lin[t*64+c], att_d[c], a);
    tmp[t] = a;
  }
  __syncthreads();
  if (t < 9){
    float a = 0.f;
    if (t < 8){ for (int k=0;k<64;++k) a = fmaf(W_well[t*64+k], tmp[k], a); }
    else      { for (int k=0;k<64;++k) a = fmaf(b_well[k],     tmp[k], a); }
    wprep[t] = a;
  }
}

__global__ void k_well_ad2(const float* __restrict__ well_x, const float* __restrict__ wprep,
                           float* __restrict__ ad_w, int n){
  int w = blockIdx.x*blockDim.x + threadIdx.x;
  if (w >= n) return;
  float a = wprep[8];
  #pragma unroll
  for (int r=0;r<8;++r) a = fmaf(well_x[w*8+r], wprep[r], a);
  ad_w[w] = a;
}

// single-pass cell bucket build: one atomic + one 8B scatter per edge
__global__ void k_build_cc(const int* __restrict__ src, const int* __restrict__ dst,
                           const float* __restrict__ attr, int* __restrict__ deg,
                           int2* __restrict__ slot, int4* __restrict__ ovf,
                           int* __restrict__ n_ovf, int e){
  int stride = gridDim.x*blockDim.x;
  for (int i = blockIdx.x*blockDim.x + threadIdx.x; i < e; i += stride){
    int d = dst[i];
    int off = atomicAdd(&deg[d], 1);
    if (off < CCAP){
      slot[(d<<5) + off] = make_int2(src[i], __float_as_int(attr[i]));
    } else {
      int x = atomicAdd(n_ovf, 1);
      if (x < OVF_CAP) ovf[x] = make_int4(d, src[i], __float_as_int(attr[i]), 0);
    }
  }
}

__global__ void k_count_w(const int* __restrict__ dst, int* __restrict__ deg,
                          int* __restrict__ off, int e){
  int i = blockIdx.x*blockDim.x + threadIdx.x;
  if (i<e) off[i] = atomicAdd(&deg[dst[i]], 1);
}

__global__ void k_scan_single(const int* __restrict__ deg, int* __restrict__ rowptr, int n){
  __shared__ int sm[1024];
  int t = threadIdx.x;
  sm[t] = (t<n) ? deg[t] : 0; __syncthreads();
  for (int o=1;o<blockDim.x;o<<=1){
    int v = (t>=o)?sm[t-o]:0; __syncthreads();
    sm[t]+=v; __syncthreads();
  }
  if (t<n) rowptr[t+1]=sm[t];
  if (t==0) rowptr[0]=0;
}

__global__ void k_fill_w(const int* __restrict__ src, const int* __restrict__ dst,
                         const int* __restrict__ rowptr, const int* __restrict__ off,
                         int* __restrict__ slot, int e){
  int i = blockIdx.x*blockDim.x + threadIdx.x;
  if (i>=e) return;
  int d = dst[i];
  slot[rowptr[d] + off[i]] = src[i];
}

// MFMA GEMM: hs[n,64](f16) = h[n,64](f16) @ W[64,64](f32->f16), f32 accum.
// as_[i] = hs_row . att_s ; ad_[i] = hs_row . att_d (from f32 accumulators).
// Fragments (16x16x32_f16): A lane l: row=l&15, k=(l>>4)*8+j. B lane l: col=l&15,
// k=(l>>4)*8+j (staged transposed). C/D lane l reg r: row=(l>>4)*4+r, col=l&15.
__global__ __launch_bounds__(256) void k_gemm64m(
    const __half* __restrict__ h, const float* __restrict__ W,
    const float* __restrict__ att_s, const float* __restrict__ att_d,
    __half* __restrict__ hs, float* __restrict__ as_, float* __restrict__ ad_, int n){
  __shared__ _Float16 hT[64][72];   // node-major, pad 72 -> 4-way-min LDS aliasing
  __shared__ _Float16 wT[64][72];   // transposed: wT[feat][k]
  int t = threadIdx.x;
  int n0 = blockIdx.x * 64;
  for (int i=t; i<1024; i+=256){            // W stage (transpose + cvt)
    int k = i >> 4, f4 = (i & 15) << 2;
    float4 w4 = *(const float4*)&W[k*64 + f4];
    wT[f4+0][k] = (_Float16)w4.x;
    wT[f4+1][k] = (_Float16)w4.y;
    wT[f4+2][k] = (_Float16)w4.z;
    wT[f4+3][k] = (_Float16)w4.w;
  }
  for (int i=t; i<512; i+=256){             // h stage (16B chunks)
    int node = i >> 3, c8 = (i & 7) << 3;
    int gn = n0 + node;
    if (gn < n){
      *(f16x8*)&hT[node][c8] = *(const f16x8*)&h[(size_t)gn*64 + c8];
    } else {
      f16x8 z = {0,0,0,0,0,0,0,0};
      *(f16x8*)&hT[node][c8] = z;
    }
  }
  __syncthreads();
  int w = t >> 6, lane = t & 63;
  int lr = lane & 15, lg = lane >> 4;
  f32x4 acc[4];
  #pragma unroll
  for (int c=0;c<4;++c) acc[c] = (f32x4){0.f,0.f,0.f,0.f};
  #pragma unroll
  for (int kk=0; kk<2; ++kk){
    f16x8 a = *(const f16x8*)&hT[16*w + lr][kk*32 + lg*8];
    #pragma unroll
    for (int c=0;c<4;++c){
      f16x8 b = *(const f16x8*)&wT[16*c + lr][kk*32 + lg*8];
      acc[c] = __builtin_amdgcn_mfma_f32_16x16x32_f16(a, b, acc[c], 0, 0, 0);
    }
  }
  float s_att[4], d_att[4];
  #pragma unroll
  for (int c=0;c<4;++c){ s_att[c]=att_s[16*c+lr]; d_att[c]=att_d[16*c+lr]; }
  #pragma unroll
  for (int r=0;r<4;++r){
    int gn = n0 + 16*w + lg*4 + r;
    float sv=0.f, dv=0.f;
    if (gn < n){
      #pragma unroll
      for (int c=0;c<4;++c){
        float v = acc[c][r];
        hs[(size_t)gn*64 + 16*c + lr] = __float2half(v);
        sv = fmaf(v, s_att[c], sv);
        dv = fmaf(v, d_att[c], dv);
      }
    }
    #pragma unroll
    for (int o=8;o;o>>=1){ sv += __shfl_xor(sv,o,16); dv += __shfl_xor(dv,o,16); }
    if (gn < n && lr==0){ as_[gn]=sv; ad_[gn]=dv; }
  }
}

// layer-0 fused: hs = x[n,12] @ Weff[12,64] + beff (f32 VALU; K=12)
__global__ __launch_bounds__(256) void k_gemm_l0(
    const float* __restrict__ x, const float* __restrict__ weff,
    const float* __restrict__ att_s, const float* __restrict__ att_d,
    __half* __restrict__ hs, float* __restrict__ as_, float* __restrict__ ad_, int n){
  __shared__ float Ws[12*64];
  __shared__ float xT[12][68];
  int t = threadIdx.x;
  int n0 = blockIdx.x * 64;
  for (int i=t;i<768;i+=256){
    Ws[i] = weff[i];
    int node = i / 12, r = i - node*12;
    int gn = n0 + node;
    xT[r][node] = (gn < n) ? x[(size_t)gn*12 + r] : 0.f;
  }
  __syncthreads();
  int tx = t & 15, ty = t >> 4;
  int f4 = tx*4;
  float4 be = *(const float4*)&weff[768 + f4];
  float acc[4][4];
  #pragma unroll
  for (int i=0;i<4;++i){ acc[i][0]=be.x; acc[i][1]=be.y; acc[i][2]=be.z; acc[i][3]=be.w; }
  #pragma unroll
  for (int k=0;k<12;++k){
    float4 wv = *(const float4*)&Ws[k*64 + f4];
    float hvv[4];
    #pragma unroll
    for (int i=0;i<4;++i) hvv[i] = xT[k][ty*4+i];
    float wvv[4] = {wv.x,wv.y,wv.z,wv.w};
    #pragma unroll
    for (int i=0;i<4;++i)
      #pragma unroll
      for (int j=0;j<4;++j)
        acc[i][j] = fmaf(hvv[i], wvv[j], acc[i][j]);
  }
  float4 s4 = *(const float4*)&att_s[f4];
  float4 d4 = *(const float4*)&att_d[f4];
  #pragma unroll
  for (int i=0;i<4;++i){
    int gn = n0 + ty*4 + i;
    if (gn < n){
      union { __half2 h2; unsigned u; } lo, hi;
      lo.h2 = __floats2half2_rn(acc[i][0], acc[i][1]);
      hi.h2 = __floats2half2_rn(acc[i][2], acc[i][3]);
      *(int2*)&hs[(size_t)gn*64 + f4] = make_int2((int)lo.u, (int)hi.u);
      float sv = acc[i][0]*s4.x + acc[i][1]*s4.y + acc[i][2]*s4.z + acc[i][3]*s4.w;
      float dv = acc[i][0]*d4.x + acc[i][1]*d4.y + acc[i][2]*d4.z + acc[i][3]*d4.w;
      #pragma unroll
      for (int o=8;o;o>>=1){ sv += __shfl_xor(sv,o); dv += __shfl_xor(dv,o); }
      if (tx==0){ as_[gn]=sv; ad_[gn]=dv; }
    }
  }
}

// cell aggregation over fixed-stride buckets (CAP=32) + rare overflow list.
// 16-lane group per dst node; output h_cur in fp16.
template<bool RELU>
__global__ __launch_bounds__(256) void k_gat_agg3(
    const int* __restrict__ deg, const int2* __restrict__ slot,
    const int4* __restrict__ ovf, const int* __restrict__ n_ovf_p,
    const float* __restrict__ as_, const float* __restrict__ ad_,
    const __half* __restrict__ hs, const float* __restrict__ bias,
    const float* __restrict__ escal, int l,
    __half* __restrict__ out, int n){
  int t = threadIdx.x;
  int g = t & 15;
  int node = blockIdx.x*16 + (t >> 4);
  if (node >= n) return;
  int degn = deg[node];
  float4 b4 = *(const float4*)&bias[g*4];
  if (degn == 0){
    float4 r = b4;
    if (RELU){ r.x=fmaxf(r.x,0.f); r.y=fmaxf(r.y,0.f); r.z=fmaxf(r.z,0.f); r.w=fmaxf(r.w,0.f); }
    union { __half2 h2[2]; int2 i2; } u;
    u.h2[0] = __floats2half2_rn(r.x, r.y);
    u.h2[1] = __floats2half2_rn(r.z, r.w);
    *(int2*)&out[(size_t)node*64 + g*4] = u.i2;
    return;
  }
  float se = escal[l], oe = escal[3+l];
  float adn = ad_[node];
  int cin = min(degn, CCAP);
  int sb = node << 5;
  float areg[2]; int sreg[2];
  float m = -1e30f;
  #pragma unroll
  for (int it=0; it<2; ++it){
    int k = it*16 + g;
    areg[it] = -1e30f; sreg[it] = 0;
    if (k < cin){
      int2 sv = slot[sb + k];
      float a = as_[sv.x] + adn;
      a = fmaf(__int_as_float(sv.y), se, a) + oe;
      a = (a >= 0.f) ? a : 0.2f*a;
      areg[it] = a; sreg[it] = sv.x;
      m = fmaxf(m, a);
    }
  }
  int no = 0;
  if (degn > CCAP) no = min(*n_ovf_p, OVF_CAP);
  for (int j=0;j<no;++j){
    int4 e = ovf[j];
    if (e.x == node){
      float a = as_[e.y] + adn;
      a = fmaf(__int_as_float(e.z), se, a) + oe;
      a = (a >= 0.f) ? a : 0.2f*a;
      m = fmaxf(m, a);
    }
  }
  #pragma unroll
  for (int o=8;o;o>>=1) m = fmaxf(m, __shfl_xor(m, o, 16));

  float sum = 0.f;
  float4 acc = make_float4(0.f,0.f,0.f,0.f);
  #pragma unroll
  for (int it=0; it<2; ++it){
    int base = it*16;
    if (base < cin){
      float p = (base + g < cin) ? __expf(areg[it] - m) : 0.f;
      sum += p;
      int cnt = min(16, cin - base);
      for (int j=0;j<cnt;j+=4){
        float pj[4]; int sj[4];
        int s0 = __shfl(sreg[it], j, 16);
        #pragma unroll
        for (int u=0;u<4;++u){
          int jj = j+u;
          bool act = (jj < cnt);
          pj[u] = act ? __shfl(p, jj, 16) : 0.f;
          int sv = __shfl(sreg[it], act ? jj : j, 16);
          sj[u] = act ? sv : s0;
        }
        int2 hb[4];
        #pragma unroll
        for (int u=0;u<4;++u) hb[u] = *(const int2*)&hs[(size_t)sj[u]*64 + g*4];
        #pragma unroll
        for (int u=0;u<4;++u){
          union { unsigned u32; __half2 h2; } a0, a1;
          a0.u32 = (unsigned)hb[u].x; a1.u32 = (unsigned)hb[u].y;
          float2 f0 = __half22float2(a0.h2);
          float2 f1 = __half22float2(a1.h2);
          acc.x = fmaf(f0.x, pj[u], acc.x);
          acc.y = fmaf(f0.y, pj[u], acc.y);
          acc.z = fmaf(f1.x, pj[u], acc.z);
          acc.w = fmaf(f1.y, pj[u], acc.w);
        }
      }
    }
  }
  for (int j=0;j<no;++j){
    int4 e = ovf[j];
    if (e.x == node){
      float a = as_[e.y] + adn;
      a = fmaf(__int_as_float(e.z), se, a) + oe;
      a = (a >= 0.f) ? a : 0.2f*a;
      float p = __expf(a - m);
      if (g == 0) sum += p;
      int2 hb = *(const int2*)&hs[(size_t)e.y*64 + g*4];
      union { unsigned u; __half2 h2; } a0, a1; a0.u = (unsigned)hb.x; a1.u = (unsigned)hb.y;
      float2 f0 = __half22float2(a0.h2);
      float2 f1 = __half22float2(a1.h2);
      acc.x = fmaf(f0.x, p, acc.x);
      acc.y = fmaf(f0.y, p, acc.y);
      acc.z = fmaf(f1.x, p, acc.z);
      acc.w = fmaf(f1.y, p, acc.w);
    }
  }
  #pragma unroll
  for (int o=8;o;o>>=1) sum += __shfl_xor(sum, o, 16);
  float4 r;
  r.x = acc.x/sum + b4.x;
  r.y = acc.y/sum + b4.y;
  r.z = acc.z/sum + b4.z;
  r.w = acc.w/sum + b4.w;
  if (RELU){ r.x=fmaxf(r.x,0.f); r.y=fmaxf(r.y,0.f); r.z=fmaxf(r.z,0.f); r.w=fmaxf(r.w,0.f); }
  union { __half2 h2[2]; int2 i2; } u;
  u.h2[0] = __floats2half2_rn(r.x, r.y);
  u.h2[1] = __floats2half2_rn(r.z, r.w);
  *(int2*)&out[(size_t)node*64 + g*4] = u.i2;
}

// well aggregation (CSR rowptr, int slots, no attr, no relu, f32 out)
template<int NA>
__global__ __launch_bounds__(256) void k_gat_aggw(
    const int* __restrict__ rowptr, const int* __restrict__ slot1,
    float* __restrict__ alpha_ws,
    const float* __restrict__ as_, const float* __restrict__ ad_,
    const __half* __restrict__ hs, const float* __restrict__ bias,
    float* __restrict__ out, int n){
  int t = threadIdx.x;
  int g = t & 15;
  int node = blockIdx.x*16 + (t >> 4);
  if (node >= n) return;
  int beg = rowptr[node], end = rowptr[node+1];
  float4 b4 = *(const float4*)&bias[g*4];
  if (end == beg){
    *(float4*)&out[(size_t)node*64 + g*4] = b4;
    return;
  }
  float adn = ad_[node];
  float areg[NA]; int sreg[NA];
  float m = -1e30f;
  #pragma unroll
  for (int it=0; it<NA; ++it){
    int k = beg + it*16 + g;
    areg[it] = -1e30f; sreg[it] = 0;
    if (k < end){
      int s = slot1[k];
      float a = as_[s] + adn;
      a = (a >= 0.f) ? a : 0.2f*a;
      areg[it] = a; sreg[it] = s;
      m = fmaxf(m, a);
    }
  }
  for (int k = beg + NA*16 + g; k < end; k += 16){
    int s = slot1[k];
    float a = as_[s] + adn;
    a = (a >= 0.f) ? a : 0.2f*a;
    alpha_ws[k] = a;
    m = fmaxf(m, a);
  }
  #pragma unroll
  for (int o=8;o;o>>=1) m = fmaxf(m, __shfl_xor(m, o, 16));

  float sum = 0.f;
  float4 acc = make_float4(0.f,0.f,0.f,0.f);
  #pragma unroll
  for (int it=0; it<NA; ++it){
    int base = beg + it*16;
    if (base < end){
      float p = (base + g < end) ? __expf(areg[it] - m) : 0.f;
      sum += p;
      int cnt = min(16, end - base);
      for (int j=0;j<cnt;++j){
        float pj = __shfl(p, j, 16);
        int   sj = __shfl(sreg[it], j, 16);
        int2 hb = *(const int2*)&hs[(size_t)sj*64 + g*4];
        union { unsigned u; __half2 h2; } a0, a1; a0.u = (unsigned)hb.x; a1.u = (unsigned)hb.y;
        float2 f0 = __half22float2(a0.h2);
        float2 f1 = __half22float2(a1.h2);
        acc.x = fmaf(f0.x, pj, acc.x);
        acc.y = fmaf(f0.y, pj, acc.y);
        acc.z = fmaf(f1.x, pj, acc.z);
        acc.w = fmaf(f1.y, pj, acc.w);
      }
    }
  }
  for (int base = beg + NA*16; base < end; base += 16){
    int k = base + g;
    float p = 0.f; int s = 0;
    if (k < end){ s = slot1[k]; p = __expf(alpha_ws[k] - m); }
    sum += p;
    int cnt = min(16, end - base);
    for (int j=0;j<cnt;++j){
      float pj = __shfl(p, j, 16);
      int   sj = __shfl(s, j, 16);
      int2 hb = *(const int2*)&hs[(size_t)sj*64 + g*4];
      union { unsigned u; __half2 h2; } a0, a1; a0.u = (unsigned)hb.x; a1.u = (unsigned)hb.y;
      float2 f0 = __half22float2(a0.h2);
      float2 f1 = __half22float2(a1.h2);
      acc.x = fmaf(f0.x, pj, acc.x);
      acc.y = fmaf(f0.y, pj, acc.y);
      acc.z = fmaf(f1.x, pj, acc.z);
      acc.w = fmaf(f1.y, pj, acc.w);
    }
  }
  #pragma unroll
  for (int o=8;o;o>>=1) sum += __shfl_xor(sum, o, 16);
  float4 r;
  r.x = acc.x/sum + b4.x;
  r.y = acc.y/sum + b4.y;
  r.z = acc.z/sum + b4.z;
  r.w = acc.w/sum + b4.w;
  *(float4*)&out[(size_t)node*64 + g*4] = r;
}

__global__ __launch_bounds__(128) void k_mlp(const float* __restrict__ h_well,
    const float* __restrict__ W1, const float* __restrict__ b1,
    const float* __restrict__ W2, const float* __restrict__ b2,
    float* __restrict__ out, int n){
  __shared__ float hr[64]; __shared__ float h1[64];
  int w = blockIdx.x, t = threadIdx.x;
  if (t<64) hr[t] = h_well[w*64+t];
  __syncthreads();
  if (t<64){
    float a = b1[t];
    for (int k=0;k<64;++k) a = fmaf(hr[k], W1[k*64+t], a);
    h1[t] = fmaxf(a, 0.f);
  }
  __syncthreads();
  if (t<75){
    float a = b2[t];
    for (int k=0;k<64;++k) a = fmaf(h1[k], W2[k*75+t], a);
    out[w*75+t] = a;
  }
}

extern "C" void kernel_launch(void* const* d_in, const int* in_sizes, int n_in,
                              void* d_out, int out_size, void* d_ws, size_t ws_size,
                              hipStream_t stream){
  const float* cell_x = (const float*)d_in[0];
  const float* well_x = (const float*)d_in[1];
  const float* eattr  = (const float*)d_in[2];
  const int*   cc_idx = (const int*)d_in[3];
  const int*   cw_idx = (const int*)d_in[4];
  const float* W_cell = (const float*)d_in[5];
  const float* b_cell = (const float*)d_in[6];
  const float* W_well = (const float*)d_in[7];
  const float* b_well = (const float*)d_in[8];
  const float* W_edge = (const float*)d_in[9];
  const float* b_edge = (const float*)d_in[10];
  const float* conv_lin = (const float*)d_in[11];
  const float* conv_lin_edge = (const float*)d_in[12];
  const float* att_src = (const float*)d_in[13];
  const float* att_dst = (const float*)d_in[14];
  const float* att_edge = (const float*)d_in[15];
  const float* conv_bias = (const float*)d_in[16];
  const float* wc_lin = (const float*)d_in[17];
  const float* wc_att_src = (const float*)d_in[18];
  const float* wc_att_dst = (const float*)d_in[19];
  const float* wc_bias = (const float*)d_in[20];
  const float* mlp_W1 = (const float*)d_in[21];
  const float* mlp_b1 = (const float*)d_in[22];
  const float* mlp_W2 = (const float*)d_in[23];
  const float* mlp_b2 = (const float*)d_in[24];

  int n_cell = in_sizes[0]/12;
  int n_well = in_sizes[1]/8;
  int e_cc = in_sizes[2];
  int e_cw = in_sizes[4]/2;

  const int* cc_src = cc_idx;
  const int* cc_dst = cc_idx + e_cc;
  const int* cw_src = cw_idx;
  const int* cw_dst = cw_idx + e_cw;

  char* p = (char*)d_ws;
  auto alloc = [&](size_t bytes)->void*{
    void* r = (void*)p;
    p += (bytes + 255) & ~(size_t)255;
    return r;
  };
  __half* h_cur = (__half*)alloc((size_t)n_cell*64*2);
  __half* hs   = (__half*)alloc((size_t)n_cell*64*2);
  float* as_   = (float*)alloc((size_t)n_cell*4);
  float* ad_   = (float*)alloc((size_t)n_cell*4);
  int* deg     = (int*)alloc((size_t)n_cell*4);
  int2* slot2  = (int2*)alloc((size_t)n_cell*CCAP*8);
  int4* ovf    = (int4*)alloc((size_t)OVF_CAP*16);
  int* n_ovf   = (int*)alloc(256);
  float* ad_w  = (float*)alloc((size_t)n_well*4);
  int* wdeg    = (int*)alloc((size_t)n_well*4);
  int* wrowptr = (int*)alloc((size_t)(n_well+1)*4);
  int* woff    = (int*)alloc((size_t)e_cw*4);
  int* wslot   = (int*)alloc((size_t)e_cw*4);
  float* walpha= (float*)alloc((size_t)e_cw*4);
  float* h_well= (float*)alloc((size_t)n_well*64*4);
  float* escal = (float*)alloc(64);
  float* weff  = (float*)alloc(832*4);
  float* wprep = (float*)alloc(16*4);

  hipMemsetAsync(deg, 0, (size_t)n_cell*4, stream);
  hipMemsetAsync(wdeg, 0, (size_t)n_well*4, stream);
  hipMemsetAsync(n_ovf, 0, 4, stream);

  // precomputed small tensors
  k_edge_scalars<<<1, 192, 0, stream>>>(conv_lin_edge, att_edge, W_edge, b_edge, escal);
  k_prepA<<<1, 256, 0, stream>>>(W_cell, b_cell, conv_lin, weff);
  k_prepB<<<1, 128, 0, stream>>>(W_well, b_well, wc_lin, wc_att_dst, wprep);

  // single-pass cell bucket build
  int gB = (e_cc + 255)/256; if (gB > 2048) gB = 2048;
  k_build_cc<<<gB, 256, 0, stream>>>(cc_src, cc_dst, eattr, deg, slot2, ovf, n_ovf, e_cc);

  // wells: exact CSR (tiny)
  k_count_w<<<(e_cw+255)/256, 256, 0, stream>>>(cw_dst, wdeg, woff, e_cw);
  k_scan_single<<<1, 512, 0, stream>>>(wdeg, wrowptr, n_well);
  k_fill_w<<<(e_cw+255)/256, 256, 0, stream>>>(cw_src, cw_dst, wrowptr, woff, wslot, e_cw);

  // layer 0: fused embed+gemm reading cell_x directly
  k_gemm_l0<<<(n_cell+63)/64, 256, 0, stream>>>(cell_x, weff,
      att_src, att_dst, hs, as_, ad_, n_cell);
  k_gat_agg3<true><<<(n_cell+15)/16, 256, 0, stream>>>(deg, slot2, ovf, n_ovf,
      as_, ad_, hs, conv_bias, escal, 0, h_cur, n_cell);

  // layers 1,2 (MFMA GEMM)
  for (int l=1;l<3;++l){
    k_gemm64m<<<(n_cell+63)/64, 256, 0, stream>>>(h_cur, conv_lin + l*4096,
        att_src + l*64, att_dst + l*64, hs, as_, ad_, n_cell);
    k_gat_agg3<true><<<(n_cell+15)/16, 256, 0, stream>>>(deg, slot2, ovf, n_ovf,
        as_, ad_, hs, conv_bias + l*64, escal, l, h_cur, n_cell);
  }

  // well GAT (MFMA GEMM for src transform)
  k_gemm64m<<<(n_cell+63)/64, 256, 0, stream>>>(h_cur, wc_lin, wc_att_src, wc_att_dst,
      hs, as_, ad_, n_cell);
  k_well_ad2<<<(n_well+255)/256, 256, 0, stream>>>(well_x, wprep, ad_w, n_well);
  k_gat_aggw<16><<<(n_well+15)/16, 256, 0, stream>>>(wrowptr, wslot,
      walpha, as_, ad_w, hs, wc_bias, h_well, n_well);

  // MLP head
  k_mlp<<<n_well, 128, 0, stream>>>(h_well, mlp_W1, mlp_b1, mlp_W2, mlp_b2, (float*)d_out, n_well);
}

// Round 11
// 525.363 us; speedup vs baseline: 1.7739x; 1.0167x over previous
//
#include <hip/hip_runtime.h>
#include <hip/hip_fp16.h>
#include <math.h>

#define CCAP 32
#define OVF_CAP 8192

typedef __attribute__((ext_vector_type(8))) _Float16 f16x8;
typedef __attribute__((ext_vector_type(4))) float f32x4;

__device__ __forceinline__ float wsum(float v){
  #pragma unroll
  for (int o=32;o;o>>=1) v += __shfl_xor(v,o);
  return v;
}

// escal[l] = W_edge_row . (lin_edge_l @ att_e_l); escal[3+l] = b_edge . (...)
__global__ void k_edge_scalars(const float* __restrict__ lin_edge,
                               const float* __restrict__ att_e,
                               const float* __restrict__ Wrow,
                               const float* __restrict__ bemb,
                               float* __restrict__ escal){
  int l = threadIdx.x >> 6, j = threadIdx.x & 63;
  float v = 0.f;
  for (int k=0;k<64;++k) v = fmaf(lin_edge[l*4096 + j*64 + k], att_e[l*64+k], v);
  float sv = wsum(Wrow[j]*v);
  float ov = wsum(bemb[j]*v);
  if (j==0){ escal[l]=sv; escal[3+l]=ov; }
}

// Weff[12][64] = W_cell @ lin0 ; beff[64] = b_cell @ lin0
__global__ void k_prepA(const float* __restrict__ W_cell, const float* __restrict__ b_cell,
                        const float* __restrict__ lin0, float* __restrict__ weff){
  int t = threadIdx.x;
  for (int o=t; o<832; o+=256){
    float acc = 0.f;
    if (o < 768){
      int r = o >> 6, c2 = o & 63;
      for (int c=0;c<64;++c) acc = fmaf(W_cell[r*64+c], lin0[c*64+c2], acc);
    } else {
      int c2 = o - 768;
      for (int c=0;c<64;++c) acc = fmaf(b_cell[c], lin0[c*64+c2], acc);
    }
    weff[o] = acc;
  }
}

// wv8[r] = W_well_r . (wc_lin @ att_d); wprep[8] = b_well . (wc_lin @ att_d)
__global__ void k_prepB(const float* __restrict__ W_well, const float* __restrict__ b_well,
                        const float* __restrict__ wc_lin, const float* __restrict__ att_d,
                        float* __restrict__ wprep){
  __shared__ float tmp[64];
  int t = threadIdx.x;
  if (t < 64){
    float a = 0.f;
    for (int c=0;c<64;++c) a = fmaf(wc_lin[t*64+c], att_d[c], a);
    tmp[t] = a;
  }
  __syncthreads();
  if (t < 9){
    float a = 0.f;
    if (t < 8){ for (int k=0;k<64;++k) a = fmaf(W_well[t*64+k], tmp[k], a); }
    else      { for (int k=0;k<64;++k) a = fmaf(b_well[k],     tmp[k], a); }
    wprep[t] = a;
  }
}

// single-pass cell bucket build: one atomic + one 8B scatter per edge
__global__ void k_build_cc(const int* __restrict__ src, const int* __restrict__ dst,
                           const float* __restrict__ attr, int* __restrict__ deg,
                           int2* __restrict__ slot, int4* __restrict__ ovf,
                           int* __restrict__ n_ovf, int e){
  int stride = gridDim.x*blockDim.x;
  for (int i = blockIdx.x*blockDim.x + threadIdx.x; i < e; i += stride){
    int d = dst[i];
    int off = atomicAdd(&deg[d], 1);
    if (off < CCAP){
      slot[(d<<5) + off] = make_int2(src[i], __float_as_int(attr[i]));
    } else {
      int x = atomicAdd(n_ovf, 1);
      if (x < OVF_CAP) ovf[x] = make_int4(d, src[i], __float_as_int(attr[i]), 0);
    }
  }
}

__global__ void k_count_w(const int* __restrict__ dst, int* __restrict__ deg,
                          int* __restrict__ off, int e){
  int i = blockIdx.x*blockDim.x + threadIdx.x;
  if (i<e) off[i] = atomicAdd(&deg[dst[i]], 1);
}

__global__ void k_scan_single(const int* __restrict__ deg, int* __restrict__ rowptr, int n){
  __shared__ int sm[1024];
  int t = threadIdx.x;
  sm[t] = (t<n) ? deg[t] : 0; __syncthreads();
  for (int o=1;o<blockDim.x;o<<=1){
    int v = (t>=o)?sm[t-o]:0; __syncthreads();
    sm[t]+=v; __syncthreads();
  }
  if (t<n) rowptr[t+1]=sm[t];
  if (t==0) rowptr[0]=0;
}

__global__ void k_fill_w(const int* __restrict__ src, const int* __restrict__ dst,
                         const int* __restrict__ rowptr, const int* __restrict__ off,
                         int* __restrict__ slot, int e){
  int i = blockIdx.x*blockDim.x + threadIdx.x;
  if (i>=e) return;
  int d = dst[i];
  slot[rowptr[d] + off[i]] = src[i];
}

// MFMA GEMM: hs[n,64](f16) = h[n,64](f16) @ W[64,64](f32->f16), f32 accum.
__global__ __launch_bounds__(256) void k_gemm64m(
    const __half* __restrict__ h, const float* __restrict__ W,
    const float* __restrict__ att_s, const float* __restrict__ att_d,
    __half* __restrict__ hs, float* __restrict__ as_, float* __restrict__ ad_, int n){
  __shared__ _Float16 hT[64][72];
  __shared__ _Float16 wT[64][72];
  int t = threadIdx.x;
  int n0 = blockIdx.x * 64;
  for (int i=t; i<1024; i+=256){
    int k = i >> 4, f4 = (i & 15) << 2;
    float4 w4 = *(const float4*)&W[k*64 + f4];
    wT[f4+0][k] = (_Float16)w4.x;
    wT[f4+1][k] = (_Float16)w4.y;
    wT[f4+2][k] = (_Float16)w4.z;
    wT[f4+3][k] = (_Float16)w4.w;
  }
  for (int i=t; i<512; i+=256){
    int node = i >> 3, c8 = (i & 7) << 3;
    int gn = n0 + node;
    if (gn < n){
      *(f16x8*)&hT[node][c8] = *(const f16x8*)&h[(size_t)gn*64 + c8];
    } else {
      f16x8 z = {0,0,0,0,0,0,0,0};
      *(f16x8*)&hT[node][c8] = z;
    }
  }
  __syncthreads();
  int w = t >> 6, lane = t & 63;
  int lr = lane & 15, lg = lane >> 4;
  f32x4 acc[4];
  #pragma unroll
  for (int c=0;c<4;++c) acc[c] = (f32x4){0.f,0.f,0.f,0.f};
  #pragma unroll
  for (int kk=0; kk<2; ++kk){
    f16x8 a = *(const f16x8*)&hT[16*w + lr][kk*32 + lg*8];
    #pragma unroll
    for (int c=0;c<4;++c){
      f16x8 b = *(const f16x8*)&wT[16*c + lr][kk*32 + lg*8];
      acc[c] = __builtin_amdgcn_mfma_f32_16x16x32_f16(a, b, acc[c], 0, 0, 0);
    }
  }
  float s_att[4], d_att[4];
  #pragma unroll
  for (int c=0;c<4;++c){ s_att[c]=att_s[16*c+lr]; d_att[c]=att_d[16*c+lr]; }
  #pragma unroll
  for (int r=0;r<4;++r){
    int gn = n0 + 16*w + lg*4 + r;
    float sv=0.f, dv=0.f;
    if (gn < n){
      #pragma unroll
      for (int c=0;c<4;++c){
        float v = acc[c][r];
        hs[(size_t)gn*64 + 16*c + lr] = __float2half(v);
        sv = fmaf(v, s_att[c], sv);
        dv = fmaf(v, d_att[c], dv);
      }
    }
    #pragma unroll
    for (int o=8;o;o>>=1){ sv += __shfl_xor(sv,o,16); dv += __shfl_xor(dv,o,16); }
    if (gn < n && lr==0){ as_[gn]=sv; ad_[gn]=dv; }
  }
}

// layer-0 MFMA: hs = x[n,12] @ Weff[12,64] + beff. K padded 12->32 with zeros.
__global__ __launch_bounds__(256) void k_gemm_l0m(
    const float* __restrict__ x, const float* __restrict__ weff,
    const float* __restrict__ att_s, const float* __restrict__ att_d,
    __half* __restrict__ hs, float* __restrict__ as_, float* __restrict__ ad_, int n){
  __shared__ _Float16 xT[64][40];   // node-major, k 0..31 (12 real + 20 zero), pad->40
  __shared__ _Float16 wT[64][40];   // wT[feat][k]
  int t = threadIdx.x;
  int n0 = blockIdx.x * 64;
  for (int i=t; i<768; i+=256){          // x stage (12 real k per node)
    int node = i / 12, r = i - node*12;
    int gn = n0 + node;
    xT[node][r] = (gn < n) ? (_Float16)x[(size_t)gn*12 + r] : (_Float16)0.f;
  }
  for (int i=t; i<1280; i+=256){         // zero-pad k=12..31 for x
    int node = i / 20, r = 12 + (i % 20);
    xT[node][r] = (_Float16)0.f;
  }
  for (int i=t; i<768; i+=256){          // W stage (transposed)
    int k = i >> 6, f = i & 63;
    wT[f][k] = (_Float16)weff[i];
  }
  for (int i=t; i<1280; i+=256){         // zero-pad k=12..31 for W
    int f = i / 20, k = 12 + (i % 20);
    wT[f][k] = (_Float16)0.f;
  }
  __syncthreads();
  int w = t >> 6, lane = t & 63;
  int lr = lane & 15, lg = lane >> 4;
  f32x4 acc[4];
  f16x8 a = *(const f16x8*)&xT[16*w + lr][lg*8];
  #pragma unroll
  for (int c=0;c<4;++c){
    f16x8 b = *(const f16x8*)&wT[16*c + lr][lg*8];
    acc[c] = __builtin_amdgcn_mfma_f32_16x16x32_f16(a, b, (f32x4){0.f,0.f,0.f,0.f}, 0, 0, 0);
  }
  float s_att[4], d_att[4], be[4];
  #pragma unroll
  for (int c=0;c<4;++c){
    s_att[c]=att_s[16*c+lr]; d_att[c]=att_d[16*c+lr]; be[c]=weff[768 + 16*c + lr];
  }
  #pragma unroll
  for (int r=0;r<4;++r){
    int gn = n0 + 16*w + lg*4 + r;
    float sv=0.f, dv=0.f;
    if (gn < n){
      #pragma unroll
      for (int c=0;c<4;++c){
        float v = acc[c][r] + be[c];
        hs[(size_t)gn*64 + 16*c + lr] = __float2half(v);
        sv = fmaf(v, s_att[c], sv);
        dv = fmaf(v, d_att[c], dv);
      }
    }
    #pragma unroll
    for (int o=8;o;o>>=1){ sv += __shfl_xor(sv,o,16); dv += __shfl_xor(dv,o,16); }
    if (gn < n && lr==0){ as_[gn]=sv; ad_[gn]=dv; }
  }
}

// cell aggregation over fixed-stride buckets (CAP=32) + rare overflow list.
// 16-lane group per dst node; gather loop unrolled x8 (avg deg 8 -> one batch).
template<bool RELU>
__global__ __launch_bounds__(256) void k_gat_agg3(
    const int* __restrict__ deg, const int2* __restrict__ slot,
    const int4* __restrict__ ovf, const int* __restrict__ n_ovf_p,
    const float* __restrict__ as_, const float* __restrict__ ad_,
    const __half* __restrict__ hs, const float* __restrict__ bias,
    const float* __restrict__ escal, int l,
    __half* __restrict__ out, int n){
  int t = threadIdx.x;
  int g = t & 15;
  int node = blockIdx.x*16 + (t >> 4);
  if (node >= n) return;
  int degn = deg[node];
  float4 b4 = *(const float4*)&bias[g*4];
  if (degn == 0){
    float4 r = b4;
    if (RELU){ r.x=fmaxf(r.x,0.f); r.y=fmaxf(r.y,0.f); r.z=fmaxf(r.z,0.f); r.w=fmaxf(r.w,0.f); }
    union { __half2 h2[2]; int2 i2; } u;
    u.h2[0] = __floats2half2_rn(r.x, r.y);
    u.h2[1] = __floats2half2_rn(r.z, r.w);
    *(int2*)&out[(size_t)node*64 + g*4] = u.i2;
    return;
  }
  float se = escal[l], oe = escal[3+l];
  float adn = ad_[node];
  int cin = min(degn, CCAP);
  int sb = node << 5;
  float areg[2]; int sreg[2];
  float m = -1e30f;
  #pragma unroll
  for (int it=0; it<2; ++it){
    int k = it*16 + g;
    areg[it] = -1e30f; sreg[it] = 0;
    if (k < cin){
      int2 sv = slot[sb + k];
      float a = as_[sv.x] + adn;
      a = fmaf(__int_as_float(sv.y), se, a) + oe;
      a = (a >= 0.f) ? a : 0.2f*a;
      areg[it] = a; sreg[it] = sv.x;
      m = fmaxf(m, a);
    }
  }
  int no = 0;
  if (degn > CCAP) no = min(*n_ovf_p, OVF_CAP);
  for (int j=0;j<no;++j){
    int4 e = ovf[j];
    if (e.x == node){
      float a = as_[e.y] + adn;
      a = fmaf(__int_as_float(e.z), se, a) + oe;
      a = (a >= 0.f) ? a : 0.2f*a;
      m = fmaxf(m, a);
    }
  }
  #pragma unroll
  for (int o=8;o;o>>=1) m = fmaxf(m, __shfl_xor(m, o, 16));

  float sum = 0.f;
  float4 acc = make_float4(0.f,0.f,0.f,0.f);
  #pragma unroll
  for (int it=0; it<2; ++it){
    int base = it*16;
    if (base < cin){
      float p = (base + g < cin) ? __expf(areg[it] - m) : 0.f;
      sum += p;
      int cnt = min(16, cin - base);
      for (int j=0;j<cnt;j+=8){
        float pj[8]; int sj[8];
        int s0 = __shfl(sreg[it], j, 16);
        #pragma unroll
        for (int u=0;u<8;++u){
          int jj = j+u;
          bool act = (jj < cnt);
          pj[u] = act ? __shfl(p, jj, 16) : 0.f;
          int sv = __shfl(sreg[it], act ? jj : j, 16);
          sj[u] = act ? sv : s0;
        }
        int2 hb[8];
        #pragma unroll
        for (int u=0;u<8;++u) hb[u] = *(const int2*)&hs[(size_t)sj[u]*64 + g*4];
        #pragma unroll
        for (int u=0;u<8;++u){
          union { unsigned u32; __half2 h2; } a0, a1;
          a0.u32 = (unsigned)hb[u].x; a1.u32 = (unsigned)hb[u].y;
          float2 f0 = __half22float2(a0.h2);
          float2 f1 = __half22float2(a1.h2);
          acc.x = fmaf(f0.x, pj[u], acc.x);
          acc.y = fmaf(f0.y, pj[u], acc.y);
          acc.z = fmaf(f1.x, pj[u], acc.z);
          acc.w = fmaf(f1.y, pj[u], acc.w);
        }
      }
    }
  }
  for (int j=0;j<no;++j){
    int4 e = ovf[j];
    if (e.x == node){
      float a = as_[e.y] + adn;
      a = fmaf(__int_as_float(e.z), se, a) + oe;
      a = (a >= 0.f) ? a : 0.2f*a;
      float p = __expf(a - m);
      if (g == 0) sum += p;
      int2 hb = *(const int2*)&hs[(size_t)e.y*64 + g*4];
      union { unsigned u; __half2 h2; } a0, a1; a0.u = (unsigned)hb.x; a1.u = (unsigned)hb.y;
      float2 f0 = __half22float2(a0.h2);
      float2 f1 = __half22float2(a1.h2);
      acc.x = fmaf(f0.x, p, acc.x);
      acc.y = fmaf(f0.y, p, acc.y);
      acc.z = fmaf(f1.x, p, acc.z);
      acc.w = fmaf(f1.y, p, acc.w);
    }
  }
  #pragma unroll
  for (int o=8;o;o>>=1) sum += __shfl_xor(sum, o, 16);
  float4 r;
  r.x = acc.x/sum + b4.x;
  r.y = acc.y/sum + b4.y;
  r.z = acc.z/sum + b4.z;
  r.w = acc.w/sum + b4.w;
  if (RELU){ r.x=fmaxf(r.x,0.f); r.y=fmaxf(r.y,0.f); r.z=fmaxf(r.z,0.f); r.w=fmaxf(r.w,0.f); }
  union { __half2 h2[2]; int2 i2; } u;
  u.h2[0] = __floats2half2_rn(r.x, r.y);
  u.h2[1] = __floats2half2_rn(r.z, r.w);
  *(int2*)&out[(size_t)node*64 + g*4] = u.i2;
}

// well aggregation (CSR rowptr, int slots); ad computed inline from well_x.wprep
template<int NA>
__global__ __launch_bounds__(256) void k_gat_aggw(
    const int* __restrict__ rowptr, const int* __restrict__ slot1,
    float* __restrict__ alpha_ws,
    const float* __restrict__ as_, const float* __restrict__ well_x,
    const float* __restrict__ wprep,
    const __half* __restrict__ hs, const float* __restrict__ bias,
    float* __restrict__ out, int n){
  int t = threadIdx.x;
  int g = t & 15;
  int node = blockIdx.x*16 + (t >> 4);
  if (node >= n) return;
  int beg = rowptr[node], end = rowptr[node+1];
  float4 b4 = *(const float4*)&bias[g*4];
  if (end == beg){
    *(float4*)&out[(size_t)node*64 + g*4] = b4;
    return;
  }
  float adn = wprep[8];
  #pragma unroll
  for (int r=0;r<8;++r) adn = fmaf(well_x[node*8+r], wprep[r], adn);
  float areg[NA]; int sreg[NA];
  float m = -1e30f;
  #pragma unroll
  for (int it=0; it<NA; ++it){
    int k = beg + it*16 + g;
    areg[it] = -1e30f; sreg[it] = 0;
    if (k < end){
      int s = slot1[k];
      float a = as_[s] + adn;
      a = (a >= 0.f) ? a : 0.2f*a;
      areg[it] = a; sreg[it] = s;
      m = fmaxf(m, a);
    }
  }
  for (int k = beg + NA*16 + g; k < end; k += 16){
    int s = slot1[k];
    float a = as_[s] + adn;
    a = (a >= 0.f) ? a : 0.2f*a;
    alpha_ws[k] = a;
    m = fmaxf(m, a);
  }
  #pragma unroll
  for (int o=8;o;o>>=1) m = fmaxf(m, __shfl_xor(m, o, 16));

  float sum = 0.f;
  float4 acc = make_float4(0.f,0.f,0.f,0.f);
  #pragma unroll
  for (int it=0; it<NA; ++it){
    int base = beg + it*16;
    if (base < end){
      float p = (base + g < end) ? __expf(areg[it] - m) : 0.f;
      sum += p;
      int cnt = min(16, end - base);
      for (int j=0;j<cnt;++j){
        float pj = __shfl(p, j, 16);
        int   sj = __shfl(sreg[it], j, 16);
        int2 hb = *(const int2*)&hs[(size_t)sj*64 + g*4];
        union { unsigned u; __half2 h2; } a0, a1; a0.u = (unsigned)hb.x; a1.u = (unsigned)hb.y;
        float2 f0 = __half22float2(a0.h2);
        float2 f1 = __half22float2(a1.h2);
        acc.x = fmaf(f0.x, pj, acc.x);
        acc.y = fmaf(f0.y, pj, acc.y);
        acc.z = fmaf(f1.x, pj, acc.z);
        acc.w = fmaf(f1.y, pj, acc.w);
      }
    }
  }
  for (int base = beg + NA*16; base < end; base += 16){
    int k = base + g;
    float p = 0.f; int s = 0;
    if (k < end){ s = slot1[k]; p = __expf(alpha_ws[k] - m); }
    sum += p;
    int cnt = min(16, end - base);
    for (int j=0;j<cnt;++j){
      float pj = __shfl(p, j, 16);
      int   sj = __shfl(s, j, 16);
      int2 hb = *(const int2*)&hs[(size_t)sj*64 + g*4];
      union { unsigned u; __half2 h2; } a0, a1; a0.u = (unsigned)hb.x; a1.u = (unsigned)hb.y;
      float2 f0 = __half22float2(a0.h2);
      float2 f1 = __half22float2(a1.h2);
      acc.x = fmaf(f0.x, pj, acc.x);
      acc.y = fmaf(f0.y, pj, acc.y);
      acc.z = fmaf(f1.x, pj, acc.z);
      acc.w = fmaf(f1.y, pj, acc.w);
    }
  }
  #pragma unroll
  for (int o=8;o;o>>=1) sum += __shfl_xor(sum, o, 16);
  float4 r;
  r.x = acc.x/sum + b4.x;
  r.y = acc.y/sum + b4.y;
  r.z = acc.z/sum + b4.z;
  r.w = acc.w/sum + b4.w;
  *(float4*)&out[(size_t)node*64 + g*4] = r;
}

__global__ __launch_bounds__(128) void k_mlp(const float* __restrict__ h_well,
    const float* __restrict__ W1, const float* __restrict__ b1,
    const float* __restrict__ W2, const float* __restrict__ b2,
    float* __restrict__ out, int n){
  __shared__ float hr[64]; __shared__ float h1[64];
  int w = blockIdx.x, t = threadIdx.x;
  if (t<64) hr[t] = h_well[w*64+t];
  __syncthreads();
  if (t<64){
    float a = b1[t];
    for (int k=0;k<64;++k) a = fmaf(hr[k], W1[k*64+t], a);
    h1[t] = fmaxf(a, 0.f);
  }
  __syncthreads();
  if (t<75){
    float a = b2[t];
    for (int k=0;k<64;++k) a = fmaf(h1[k], W2[k*75+t], a);
    out[w*75+t] = a;
  }
}

extern "C" void kernel_launch(void* const* d_in, const int* in_sizes, int n_in,
                              void* d_out, int out_size, void* d_ws, size_t ws_size,
                              hipStream_t stream){
  const float* cell_x = (const float*)d_in[0];
  const float* well_x = (const float*)d_in[1];
  const float* eattr  = (const float*)d_in[2];
  const int*   cc_idx = (const int*)d_in[3];
  const int*   cw_idx = (const int*)d_in[4];
  const float* W_cell = (const float*)d_in[5];
  const float* b_cell = (const float*)d_in[6];
  const float* W_well = (const float*)d_in[7];
  const float* b_well = (const float*)d_in[8];
  const float* W_edge = (const float*)d_in[9];
  const float* b_edge = (const float*)d_in[10];
  const float* conv_lin = (const float*)d_in[11];
  const float* conv_lin_edge = (const float*)d_in[12];
  const float* att_src = (const float*)d_in[13];
  const float* att_dst = (const float*)d_in[14];
  const float* att_edge = (const float*)d_in[15];
  const float* conv_bias = (const float*)d_in[16];
  const float* wc_lin = (const float*)d_in[17];
  const float* wc_att_src = (const float*)d_in[18];
  const float* wc_att_dst = (const float*)d_in[19];
  const float* wc_bias = (const float*)d_in[20];
  const float* mlp_W1 = (const float*)d_in[21];
  const float* mlp_b1 = (const float*)d_in[22];
  const float* mlp_W2 = (const float*)d_in[23];
  const float* mlp_b2 = (const float*)d_in[24];

  int n_cell = in_sizes[0]/12;
  int n_well = in_sizes[1]/8;
  int e_cc = in_sizes[2];
  int e_cw = in_sizes[4]/2;

  const int* cc_src = cc_idx;
  const int* cc_dst = cc_idx + e_cc;
  const int* cw_src = cw_idx;
  const int* cw_dst = cw_idx + e_cw;

  char* p = (char*)d_ws;
  auto alloc = [&](size_t bytes)->void*{
    void* r = (void*)p;
    p += (bytes + 255) & ~(size_t)255;
    return r;
  };
  __half* h_cur = (__half*)alloc((size_t)n_cell*64*2);
  __half* hs   = (__half*)alloc((size_t)n_cell*64*2);
  float* as_   = (float*)alloc((size_t)n_cell*4);
  float* ad_   = (float*)alloc((size_t)n_cell*4);
  int* deg     = (int*)alloc((size_t)n_cell*4);
  int2* slot2  = (int2*)alloc((size_t)n_cell*CCAP*8);
  int4* ovf    = (int4*)alloc((size_t)OVF_CAP*16);
  int* n_ovf   = (int*)alloc(256);
  int* wdeg    = (int*)alloc((size_t)n_well*4);
  int* wrowptr = (int*)alloc((size_t)(n_well+1)*4);
  int* woff    = (int*)alloc((size_t)e_cw*4);
  int* wslot   = (int*)alloc((size_t)e_cw*4);
  float* walpha= (float*)alloc((size_t)e_cw*4);
  float* h_well= (float*)alloc((size_t)n_well*64*4);
  float* escal = (float*)alloc(64);
  float* weff  = (float*)alloc(832*4);
  float* wprep = (float*)alloc(16*4);

  hipMemsetAsync(deg, 0, (size_t)n_cell*4, stream);
  hipMemsetAsync(wdeg, 0, (size_t)n_well*4, stream);
  hipMemsetAsync(n_ovf, 0, 4, stream);

  // precomputed small tensors
  k_edge_scalars<<<1, 192, 0, stream>>>(conv_lin_edge, att_edge, W_edge, b_edge, escal);
  k_prepA<<<1, 256, 0, stream>>>(W_cell, b_cell, conv_lin, weff);
  k_prepB<<<1, 128, 0, stream>>>(W_well, b_well, wc_lin, wc_att_dst, wprep);

  // single-pass cell bucket build
  int gB = (e_cc + 255)/256; if (gB > 2048) gB = 2048;
  k_build_cc<<<gB, 256, 0, stream>>>(cc_src, cc_dst, eattr, deg, slot2, ovf, n_ovf, e_cc);

  // wells: exact CSR (tiny)
  k_count_w<<<(e_cw+255)/256, 256, 0, stream>>>(cw_dst, wdeg, woff, e_cw);
  k_scan_single<<<1, 512, 0, stream>>>(wdeg, wrowptr, n_well);
  k_fill_w<<<(e_cw+255)/256, 256, 0, stream>>>(cw_src, cw_dst, wrowptr, woff, wslot, e_cw);

  // layer 0: MFMA fused embed+gemm reading cell_x directly
  k_gemm_l0m<<<(n_cell+63)/64, 256, 0, stream>>>(cell_x, weff,
      att_src, att_dst, hs, as_, ad_, n_cell);
  k_gat_agg3<true><<<(n_cell+15)/16, 256, 0, stream>>>(deg, slot2, ovf, n_ovf,
      as_, ad_, hs, conv_bias, escal, 0, h_cur, n_cell);

  // layers 1,2 (MFMA GEMM)
  for (int l=1;l<3;++l){
    k_gemm64m<<<(n_cell+63)/64, 256, 0, stream>>>(h_cur, conv_lin + l*4096,
        att_src + l*64, att_dst + l*64, hs, as_, ad_, n_cell);
    k_gat_agg3<true><<<(n_cell+15)/16, 256, 0, stream>>>(deg, slot2, ovf, n_ovf,
        as_, ad_, hs, conv_bias + l*64, escal, l, h_cur, n_cell);
  }

  // well GAT (MFMA GEMM for src transform; ad_w inline in aggw)
  k_gemm64m<<<(n_cell+63)/64, 256, 0, stream>>>(h_cur, wc_lin, wc_att_src, wc_att_dst,
      hs, as_, ad_, n_cell);
  k_gat_aggw<16><<<(n_well+15)/16, 256, 0, stream>>>(wrowptr, wslot,
      walpha, as_, well_x, wprep, hs, wc_bias, h_well, n_well);

  // MLP head
  k_mlp<<<n_well, 128, 0, stream>>>(h_well, mlp_W1, mlp_b1, mlp_W2, mlp_b2, (float*)d_out, n_well);
}